// Round 1
// baseline (746.687 us; speedup 1.0000x reference)
//
#include <hip/hip_runtime.h>
#include <hip/hip_bf16.h>
#include <stdint.h>

// Problem dims
#define NN   8192
#define FIN  128
#define DM   256
#define DI   512
#define DST  16
#define NC   128   // scan chunks
#define CL   64    // chunk length (NC*CL == NN)

typedef short bf16x8 __attribute__((ext_vector_type(8)));
typedef float f32x4 __attribute__((ext_vector_type(4)));

union FragU { unsigned u[4]; uint4 u4; bf16x8 v; };

__device__ __forceinline__ unsigned short f2bf(float x){
  unsigned u = __float_as_uint(x);
  return (unsigned short)((u + 0x7FFFu + ((u >> 16) & 1u)) >> 16);
}
__device__ __forceinline__ unsigned pack2(float a, float b){
  return (unsigned)f2bf(a) | ((unsigned)f2bf(b) << 16);
}
__device__ __forceinline__ float sigmoidf_(float x){ return 1.f / (1.f + __expf(-x)); }
__device__ __forceinline__ f32x4 zero4(){ f32x4 z; z[0]=0.f; z[1]=0.f; z[2]=0.f; z[3]=0.f; return z; }

// ---------------- workspace layout ----------------
constexpr size_t OFF_XWT   = 0;                                    // xw^T bf16 [256][8192]
constexpr size_t OFF_H     = OFF_XWT   + (size_t)DM*NN*2;          // relu(adj@xw+b) fp32 [8192][256]
constexpr size_t OFF_HBN   = OFF_H     + (size_t)NN*DM*4;          // BN'd h fp32
constexpr size_t OFF_HBNB  = OFF_HBN   + (size_t)NN*DM*4;          // BN'd h bf16
constexpr size_t OFF_WINB  = OFF_HBNB  + (size_t)NN*DM*2;          // w_in bf16 [1024][256]
constexpr size_t OFF_WXPB  = OFF_WINB  + (size_t)1024*256*2;       // w_xproj bf16 [48][512]
constexpr size_t OFF_WOUTB = OFF_WXPB  + (size_t)48*512*2;         // w_out bf16 [256][512]
constexpr size_t OFF_XZ    = OFF_WOUTB + (size_t)256*512*2;        // xz fp32 [8192][1024]
constexpr size_t OFF_XC    = OFF_XZ    + (size_t)NN*1024*4;        // xc fp32 [8192][512]
constexpr size_t OFF_XCB   = OFF_XC    + (size_t)NN*DI*4;          // xc bf16
constexpr size_t OFF_XDBL  = OFF_XCB   + (size_t)NN*DI*2;          // x_dbl fp32 [8192][48]
constexpr size_t OFF_DT    = OFF_XDBL  + (size_t)NN*48*4;          // dt fp32 [8192][512]
constexpr size_t OFF_P     = OFF_DT    + (size_t)NN*DI*4;          // chunk prod [128][8192]
constexpr size_t OFF_F     = OFF_P     + (size_t)NC*DI*DST*4;      // chunk final [128][8192]
constexpr size_t OFF_CARRY = OFF_F     + (size_t)NC*DI*DST*4;      // carry-in [128][8192]
constexpr size_t OFF_YB    = OFF_CARRY + (size_t)NC*DI*DST*4;      // gated y bf16 [8192][512]
constexpr size_t OFF_BNS   = OFF_YB    + (size_t)NN*DI*2;          // bn sums [256]
constexpr size_t OFF_BNS2  = OFF_BNS   + 256*4;                    // bn sumsq [256]
constexpr size_t WS_NEED   = OFF_BNS2  + 256*4;

// ---------------- prep: fp32 -> bf16 weight conversion ----------------
__global__ __launch_bounds__(256) void prep_kernel(
    const float* __restrict__ w_in, const float* __restrict__ w_xp, const float* __restrict__ w_out,
    unsigned short* __restrict__ o_in, unsigned short* __restrict__ o_xp, unsigned short* __restrict__ o_out)
{
  int i = blockIdx.x * 256 + threadIdx.x;
  if (i < 1024*256) o_in[i]  = f2bf(w_in[i]);
  if (i < 48*512)   o_xp[i]  = f2bf(w_xp[i]);
  if (i < 256*512)  o_out[i] = f2bf(w_out[i]);
}

// ---------------- gemm1: xw = x @ w_gcn, stored transposed bf16 [256][8192] ----------------
__global__ __launch_bounds__(256) void gemm1_kernel(
    const float* __restrict__ x, const float* __restrict__ w, unsigned short* __restrict__ xwT)
{
  __shared__ float xs[16*128];
  const int t = threadIdx.x;
  const int m0 = blockIdx.x * 16;
  {
    int r = t >> 4, c0 = (t & 15) * 8;
    const float* src = x + (size_t)(m0 + r)*FIN + c0;
    *(float4*)&xs[r*128 + c0]     = *(const float4*)src;
    *(float4*)&xs[r*128 + c0 + 4] = *(const float4*)(src + 4);
  }
  __syncthreads();
  const int n = t;
  float acc[16];
  #pragma unroll
  for (int m = 0; m < 16; ++m) acc[m] = 0.f;
  for (int k = 0; k < 128; k += 4){
    float w0 = w[(size_t)k*DM + n];
    float w1 = w[(size_t)(k+1)*DM + n];
    float w2 = w[(size_t)(k+2)*DM + n];
    float w3 = w[(size_t)(k+3)*DM + n];
    #pragma unroll
    for (int m = 0; m < 16; ++m){
      float4 xv = *(const float4*)&xs[m*128 + k];
      acc[m] = fmaf(xv.x, w0, acc[m]);
      acc[m] = fmaf(xv.y, w1, acc[m]);
      acc[m] = fmaf(xv.z, w2, acc[m]);
      acc[m] = fmaf(xv.w, w3, acc[m]);
    }
  }
  unsigned outp[8];
  #pragma unroll
  for (int m = 0; m < 8; ++m) outp[m] = pack2(acc[2*m], acc[2*m+1]);
  unsigned short* dst = xwT + (size_t)n*NN + m0;
  ((uint4*)dst)[0] = *(uint4*)&outp[0];
  ((uint4*)dst)[1] = *(uint4*)&outp[4];
}

// ---------------- gemm2: h = relu(adj @ xw + b_gcn), + BN partial stats ----------------
// M-tile 32, full N=256, 8 waves (each 32x32 wave tile), BK=64, A reg->LDS prefetch,
// B fragments direct from global xwT (L2/LLC resident, 4 MB).
__global__ __launch_bounds__(512) void gemm2_kernel(
    const float* __restrict__ adj, const unsigned short* __restrict__ xwT,
    const float* __restrict__ b_gcn, float* __restrict__ h,
    float* __restrict__ bn_sum, float* __restrict__ bn_sumsq)
{
  __shared__ unsigned a_lds[32*34];
  const int t = threadIdx.x;
  const int wave = t >> 6, lane = t & 63, r = lane & 15, q = lane >> 4;
  const int m0 = blockIdx.x * 32;
  const int nw = wave * 32;

  f32x4 acc[2][2];
  #pragma unroll
  for (int mi = 0; mi < 2; ++mi)
    #pragma unroll
    for (int ni = 0; ni < 2; ++ni) acc[mi][ni] = zero4();

  const int srow = t >> 4;         // 0..31
  const int scol = (t & 15) * 4;   // 0..60
  const float* aptr = adj + (size_t)(m0 + srow)*NN + scol;
  const unsigned short* bp0 = xwT + (size_t)(nw + r)*NN;
  const unsigned short* bp1 = xwT + (size_t)(nw + 16 + r)*NN;

  float4 av = *(const float4*)aptr;  // prefetch k0 = 0

  for (int k0 = 0; k0 < NN; k0 += 64){
    unsigned u0 = pack2(av.x, av.y);
    unsigned u1 = pack2(av.z, av.w);
    __syncthreads();
    a_lds[srow*34 + (t&15)*2]     = u0;
    a_lds[srow*34 + (t&15)*2 + 1] = u1;
    __syncthreads();
    if (k0 + 64 < NN) av = *(const float4*)(aptr + k0 + 64);  // overlap with compute
    #pragma unroll
    for (int kk = 0; kk < 64; kk += 32){
      FragU fa[2], fb[2];
      #pragma unroll
      for (int mi = 0; mi < 2; ++mi){
        int w0 = (mi*16 + r)*34 + (kk >> 1) + q*4;
        uint2 p0 = *(const uint2*)&a_lds[w0];
        uint2 p1 = *(const uint2*)&a_lds[w0 + 2];
        fa[mi].u[0] = p0.x; fa[mi].u[1] = p0.y; fa[mi].u[2] = p1.x; fa[mi].u[3] = p1.y;
      }
      fb[0].u4 = *(const uint4*)(bp0 + k0 + kk + q*8);
      fb[1].u4 = *(const uint4*)(bp1 + k0 + kk + q*8);
      #pragma unroll
      for (int mi = 0; mi < 2; ++mi)
        #pragma unroll
        for (int ni = 0; ni < 2; ++ni)
          acc[mi][ni] = __builtin_amdgcn_mfma_f32_16x16x32_bf16(fa[mi].v, fb[ni].v, acc[mi][ni], 0, 0, 0);
    }
  }

  #pragma unroll
  for (int ni = 0; ni < 2; ++ni){
    const int n = nw + ni*16 + r;
    const float bias = b_gcn[n];
    float s1 = 0.f, s2 = 0.f;
    #pragma unroll
    for (int mi = 0; mi < 2; ++mi){
      #pragma unroll
      for (int jr = 0; jr < 4; ++jr){
        const int m = m0 + mi*16 + q*4 + jr;
        float v = acc[mi][ni][jr] + bias;
        v = fmaxf(v, 0.f);
        h[(size_t)m*DM + n] = v;
        s1 += v; s2 += v*v;
      }
    }
    s1 += __shfl_xor(s1, 16); s1 += __shfl_xor(s1, 32);
    s2 += __shfl_xor(s2, 16); s2 += __shfl_xor(s2, 32);
    if (q == 0){
      atomicAdd(bn_sum + n, s1);
      atomicAdd(bn_sumsq + n, s2);
    }
  }
}

// ---------------- BN apply: h_bn (fp32 + bf16) ----------------
__global__ __launch_bounds__(256) void bnapply_kernel(
    const float* __restrict__ h, const float* __restrict__ s1, const float* __restrict__ s2,
    const float* __restrict__ gamma, const float* __restrict__ beta,
    float* __restrict__ hbn, unsigned short* __restrict__ hbnb)
{
  int i = blockIdx.x * 256 + threadIdx.x;
  int c = i & (DM - 1);
  float mean = s1[c] * (1.f / NN);
  float var  = s2[c] * (1.f / NN) - mean * mean;
  float inv  = rsqrtf(var + 1e-5f);
  float v = (h[i] - mean) * inv * gamma[c] + beta[c];
  hbn[i] = v;
  hbnb[i] = f2bf(v);
}

// ---------------- gemm3: xz = h_bn @ w_in^T  (M=8192,K=256,N=1024) ----------------
__global__ __launch_bounds__(256) void gemm3_kernel(
    const unsigned short* __restrict__ Ab, const unsigned short* __restrict__ Wb, float* __restrict__ xz)
{
  __shared__ unsigned a_lds[64*34];
  const int t = threadIdx.x;
  const int wave = t >> 6, lane = t & 63, r = lane & 15, q = lane >> 4;
  const int wm = wave & 1, wn = wave >> 1;
  const int mb = (blockIdx.x & 127) * 64;
  const int nb = (blockIdx.x >> 7) * 128;

  f32x4 acc[2][4];
  #pragma unroll
  for (int mi = 0; mi < 2; ++mi)
    #pragma unroll
    for (int ni = 0; ni < 4; ++ni) acc[mi][ni] = zero4();

  const int srow = t >> 2;           // 0..63
  const int skoff = (t & 3) * 16;    // 0,16,32,48
  const unsigned short* ap = Ab + (size_t)(mb + srow)*DM + skoff;
  const unsigned short* bp = Wb + (size_t)(nb + wn*64 + r)*DM;

  uint4 av0 = *(const uint4*)ap;
  uint4 av1 = *(const uint4*)(ap + 8);

  for (int k0 = 0; k0 < DM; k0 += 64){
    __syncthreads();
    unsigned* dst = &a_lds[srow*34 + (skoff >> 1)];
    dst[0]=av0.x; dst[1]=av0.y; dst[2]=av0.z; dst[3]=av0.w;
    dst[4]=av1.x; dst[5]=av1.y; dst[6]=av1.z; dst[7]=av1.w;
    __syncthreads();
    if (k0 + 64 < DM){ av0 = *(const uint4*)(ap + k0 + 64); av1 = *(const uint4*)(ap + k0 + 64 + 8); }
    #pragma unroll
    for (int kk = 0; kk < 64; kk += 32){
      FragU fa[2], fb[4];
      #pragma unroll
      for (int mi = 0; mi < 2; ++mi){
        int w0 = (wm*32 + mi*16 + r)*34 + (kk >> 1) + q*4;
        uint2 p0 = *(const uint2*)&a_lds[w0];
        uint2 p1 = *(const uint2*)&a_lds[w0 + 2];
        fa[mi].u[0]=p0.x; fa[mi].u[1]=p0.y; fa[mi].u[2]=p1.x; fa[mi].u[3]=p1.y;
      }
      #pragma unroll
      for (int ni = 0; ni < 4; ++ni)
        fb[ni].u4 = *(const uint4*)(bp + (size_t)ni*16*DM + k0 + kk + q*8);
      #pragma unroll
      for (int mi = 0; mi < 2; ++mi)
        #pragma unroll
        for (int ni = 0; ni < 4; ++ni)
          acc[mi][ni] = __builtin_amdgcn_mfma_f32_16x16x32_bf16(fa[mi].v, fb[ni].v, acc[mi][ni], 0, 0, 0);
    }
  }
  #pragma unroll
  for (int mi = 0; mi < 2; ++mi)
    #pragma unroll
    for (int ni = 0; ni < 4; ++ni)
      #pragma unroll
      for (int jr = 0; jr < 4; ++jr)
        xz[(size_t)(mb + wm*32 + mi*16 + q*4 + jr)*1024 + nb + wn*64 + ni*16 + r] = acc[mi][ni][jr];
}

// ---------------- conv (depthwise causal, D_CONV=4) + SiLU ----------------
__global__ __launch_bounds__(256) void conv_kernel(
    const float* __restrict__ xz, const float* __restrict__ conv_w, const float* __restrict__ conv_b,
    float* __restrict__ xc, unsigned short* __restrict__ xcb)
{
  int i = blockIdx.x * 256 + threadIdx.x;   // over 8192*512
  int d = i & (DI - 1), n = i >> 9;
  float4 w4 = *(const float4*)(conv_w + d*4);
  float s = conv_b[d];
  const float* col = xz + d;                // xm = xz[:, :512]
  if (n >= 3){
    s += col[(size_t)(n-3)*1024]*w4.x + col[(size_t)(n-2)*1024]*w4.y
       + col[(size_t)(n-1)*1024]*w4.z + col[(size_t)n*1024]*w4.w;
  } else {
    float wv[4] = {w4.x, w4.y, w4.z, w4.w};
    #pragma unroll
    for (int j = 0; j < 4; ++j){ int nn2 = n - 3 + j; if (nn2 >= 0) s += col[(size_t)nn2*1024]*wv[j]; }
  }
  float v = s * sigmoidf_(s);
  xc[i] = v;
  xcb[i] = f2bf(v);
}

// ---------------- gemm4: x_dbl = xc @ w_xproj^T  (M=8192,K=512,N=48) ----------------
__global__ __launch_bounds__(256) void gemm4_kernel(
    const unsigned short* __restrict__ Ab, const unsigned short* __restrict__ Wb, float* __restrict__ xdbl)
{
  __shared__ unsigned a_lds[64*34];
  const int t = threadIdx.x;
  const int wave = t >> 6, lane = t & 63, r = lane & 15, q = lane >> 4;
  const int mb = blockIdx.x * 64;

  f32x4 acc[3];
  #pragma unroll
  for (int ni = 0; ni < 3; ++ni) acc[ni] = zero4();

  const int srow = t >> 2;
  const int skoff = (t & 3) * 16;
  const unsigned short* ap = Ab + (size_t)(mb + srow)*DI + skoff;
  const unsigned short* bp = Wb + (size_t)r*DI;

  uint4 av0 = *(const uint4*)ap;
  uint4 av1 = *(const uint4*)(ap + 8);

  for (int k0 = 0; k0 < DI; k0 += 64){
    __syncthreads();
    unsigned* dst = &a_lds[srow*34 + (skoff >> 1)];
    dst[0]=av0.x; dst[1]=av0.y; dst[2]=av0.z; dst[3]=av0.w;
    dst[4]=av1.x; dst[5]=av1.y; dst[6]=av1.z; dst[7]=av1.w;
    __syncthreads();
    if (k0 + 64 < DI){ av0 = *(const uint4*)(ap + k0 + 64); av1 = *(const uint4*)(ap + k0 + 64 + 8); }
    #pragma unroll
    for (int kk = 0; kk < 64; kk += 32){
      FragU fa, fb[3];
      {
        int w0 = (wave*16 + r)*34 + (kk >> 1) + q*4;
        uint2 p0 = *(const uint2*)&a_lds[w0];
        uint2 p1 = *(const uint2*)&a_lds[w0 + 2];
        fa.u[0]=p0.x; fa.u[1]=p0.y; fa.u[2]=p1.x; fa.u[3]=p1.y;
      }
      #pragma unroll
      for (int ni = 0; ni < 3; ++ni)
        fb[ni].u4 = *(const uint4*)(bp + (size_t)ni*16*DI + k0 + kk + q*8);
      #pragma unroll
      for (int ni = 0; ni < 3; ++ni)
        acc[ni] = __builtin_amdgcn_mfma_f32_16x16x32_bf16(fa.v, fb[ni].v, acc[ni], 0, 0, 0);
    }
  }
  #pragma unroll
  for (int ni = 0; ni < 3; ++ni)
    #pragma unroll
    for (int jr = 0; jr < 4; ++jr)
      xdbl[(size_t)(mb + wave*16 + q*4 + jr)*48 + ni*16 + r] = acc[ni][jr];
}

// ---------------- dt = softplus(dt_r @ w_dt^T + b_dt) ----------------
__global__ __launch_bounds__(256) void dt_kernel(
    const float* __restrict__ xdbl, const float* __restrict__ w_dt, const float* __restrict__ b_dt,
    float* __restrict__ dt)
{
  __shared__ float xr[16];
  const int n = blockIdx.x >> 1;
  const int d = ((blockIdx.x & 1) << 8) + threadIdx.x;
  if (threadIdx.x < 16) xr[threadIdx.x] = xdbl[(size_t)n*48 + threadIdx.x];
  __syncthreads();
  float a = b_dt[d];
  const float4* wp = (const float4*)(w_dt + d*16);
  const float4* xp = (const float4*)xr;
  #pragma unroll
  for (int j = 0; j < 4; ++j){
    float4 w4 = wp[j]; float4 x4 = xp[j];
    a += w4.x*x4.x + w4.y*x4.y + w4.z*x4.z + w4.w*x4.w;
  }
  float o = (a > 20.f) ? a : log1pf(__expf(a));
  dt[(size_t)n*DI + d] = o;
}

// ---------------- scan phase A: per-chunk local recurrence -> P, F ----------------
__global__ __launch_bounds__(256) void scanA_kernel(
    const float* __restrict__ dt, const float* __restrict__ xc,
    const float* __restrict__ xdbl, const float* __restrict__ A_log,
    float* __restrict__ Pm, float* __restrict__ Fm)
{
  __shared__ float Bs[CL*DST];
  const int t = threadIdx.x;
  const int c = blockIdx.x >> 1;
  const int d = ((blockIdx.x & 1) << 8) + t;
  #pragma unroll
  for (int j = 0; j < (CL*DST)/256; ++j){
    int idx = t + 256*j;
    Bs[idx] = xdbl[(size_t)(c*CL + (idx >> 4))*48 + 16 + (idx & 15)];
  }
  __syncthreads();
  float Av[DST], hs[DST];
  {
    const float4* Ap = (const float4*)(A_log + d*DST);
    #pragma unroll
    for (int s4 = 0; s4 < 4; ++s4){
      float4 a4 = Ap[s4];
      Av[s4*4+0] = -__expf(a4.x); Av[s4*4+1] = -__expf(a4.y);
      Av[s4*4+2] = -__expf(a4.z); Av[s4*4+3] = -__expf(a4.w);
    }
  }
  #pragma unroll
  for (int s = 0; s < DST; ++s) hs[s] = 0.f;
  float sdt = 0.f;
  for (int tt = 0; tt < CL; ++tt){
    const int tg = c*CL + tt;
    float dtv = dt[(size_t)tg*DI + d];
    float xcv = xc[(size_t)tg*DI + d];
    float u = dtv * xcv;
    sdt += dtv;
    #pragma unroll
    for (int s = 0; s < DST; ++s){
      float dA = __expf(dtv * Av[s]);
      hs[s] = dA*hs[s] + u*Bs[tt*DST + s];
    }
  }
  const size_t base = (size_t)c*(DI*DST) + (size_t)d*DST;
  #pragma unroll
  for (int s = 0; s < DST; ++s) Fm[base + s] = hs[s];
  #pragma unroll
  for (int s = 0; s < DST; ++s) Pm[base + s] = __expf(Av[s]*sdt);
}

// ---------------- scan phase B: sequential carry across chunks ----------------
__global__ __launch_bounds__(256) void scanB_kernel(
    const float* __restrict__ Pm, const float* __restrict__ Fm, float* __restrict__ Cy)
{
  const int ds = blockIdx.x * 256 + threadIdx.x;   // 0..8191
  float cy = 0.f;
  Cy[ds] = 0.f;
  #pragma unroll 4
  for (int c = 1; c < NC; ++c){
    size_t prev = (size_t)(c-1)*(DI*DST) + ds;
    cy = Pm[prev]*cy + Fm[prev];
    Cy[(size_t)c*(DI*DST) + ds] = cy;
  }
}

// ---------------- scan phase C: recompute with carry, emit gated y (bf16) ----------------
__global__ __launch_bounds__(256) void scanC_kernel(
    const float* __restrict__ dt, const float* __restrict__ xc,
    const float* __restrict__ xdbl, const float* __restrict__ A_log,
    const float* __restrict__ Cy, const float* __restrict__ Dskip,
    const float* __restrict__ xz, unsigned short* __restrict__ yb)
{
  __shared__ float Bs[CL*DST];
  __shared__ float Cs[CL*DST];
  const int t = threadIdx.x;
  const int c = blockIdx.x >> 1;
  const int d = ((blockIdx.x & 1) << 8) + t;
  #pragma unroll
  for (int j = 0; j < (CL*DST)/256; ++j){
    int idx = t + 256*j;
    int tg = c*CL + (idx >> 4);
    Bs[idx] = xdbl[(size_t)tg*48 + 16 + (idx & 15)];
    Cs[idx] = xdbl[(size_t)tg*48 + 32 + (idx & 15)];
  }
  __syncthreads();
  float Av[DST], hs[DST];
  {
    const float4* Ap = (const float4*)(A_log + d*DST);
    #pragma unroll
    for (int s4 = 0; s4 < 4; ++s4){
      float4 a4 = Ap[s4];
      Av[s4*4+0] = -__expf(a4.x); Av[s4*4+1] = -__expf(a4.y);
      Av[s4*4+2] = -__expf(a4.z); Av[s4*4+3] = -__expf(a4.w);
    }
  }
  {
    const float4* hp = (const float4*)(Cy + (size_t)c*(DI*DST) + (size_t)d*DST);
    #pragma unroll
    for (int s4 = 0; s4 < 4; ++s4){
      float4 h4 = hp[s4];
      hs[s4*4+0] = h4.x; hs[s4*4+1] = h4.y; hs[s4*4+2] = h4.z; hs[s4*4+3] = h4.w;
    }
  }
  const float Dv = Dskip[d];
  for (int tt = 0; tt < CL; ++tt){
    const int tg = c*CL + tt;
    float dtv = dt[(size_t)tg*DI + d];
    float xcv = xc[(size_t)tg*DI + d];
    float u = dtv * xcv;
    float y0 = 0.f, y1 = 0.f;
    #pragma unroll
    for (int s = 0; s < DST; s += 2){
      float dA0 = __expf(dtv * Av[s]);
      float dA1 = __expf(dtv * Av[s+1]);
      hs[s]   = dA0*hs[s]   + u*Bs[tt*DST + s];
      hs[s+1] = dA1*hs[s+1] + u*Bs[tt*DST + s+1];
      y0 += hs[s]   * Cs[tt*DST + s];
      y1 += hs[s+1] * Cs[tt*DST + s+1];
    }
    float zv = xz[(size_t)tg*1024 + 512 + d];
    float yf = ((y0 + y1) + Dv*xcv) * (zv * sigmoidf_(zv));
    yb[(size_t)tg*DI + d] = f2bf(yf);
  }
}

// ---------------- gemm5: out = y @ w_out^T + h_bn  (M=8192,K=512,N=256) ----------------
__global__ __launch_bounds__(512) void gemm5_kernel(
    const unsigned short* __restrict__ yb, const unsigned short* __restrict__ Wb,
    const float* __restrict__ hbn, float* __restrict__ out)
{
  __shared__ unsigned a_lds[32*34];
  const int t = threadIdx.x;
  const int wave = t >> 6, lane = t & 63, r = lane & 15, q = lane >> 4;
  const int m0 = blockIdx.x * 32;
  const int nw = wave * 32;

  f32x4 acc[2][2];
  #pragma unroll
  for (int mi = 0; mi < 2; ++mi)
    #pragma unroll
    for (int ni = 0; ni < 2; ++ni) acc[mi][ni] = zero4();

  const int srow = t >> 4;
  const int sc = (t & 15) * 4;
  const unsigned short* ap = yb + (size_t)(m0 + srow)*DI + sc;
  const unsigned short* bp0 = Wb + (size_t)(nw + r)*DI;
  const unsigned short* bp1 = Wb + (size_t)(nw + 16 + r)*DI;

  uint2 av = *(const uint2*)ap;

  for (int k0 = 0; k0 < DI; k0 += 64){
    __syncthreads();
    a_lds[srow*34 + (t&15)*2]     = av.x;
    a_lds[srow*34 + (t&15)*2 + 1] = av.y;
    __syncthreads();
    if (k0 + 64 < DI) av = *(const uint2*)(ap + k0 + 64);
    #pragma unroll
    for (int kk = 0; kk < 64; kk += 32){
      FragU fa[2], fb[2];
      #pragma unroll
      for (int mi = 0; mi < 2; ++mi){
        int w0 = (mi*16 + r)*34 + (kk >> 1) + q*4;
        uint2 p0 = *(const uint2*)&a_lds[w0];
        uint2 p1 = *(const uint2*)&a_lds[w0 + 2];
        fa[mi].u[0]=p0.x; fa[mi].u[1]=p0.y; fa[mi].u[2]=p1.x; fa[mi].u[3]=p1.y;
      }
      fb[0].u4 = *(const uint4*)(bp0 + k0 + kk + q*8);
      fb[1].u4 = *(const uint4*)(bp1 + k0 + kk + q*8);
      #pragma unroll
      for (int mi = 0; mi < 2; ++mi)
        #pragma unroll
        for (int ni = 0; ni < 2; ++ni)
          acc[mi][ni] = __builtin_amdgcn_mfma_f32_16x16x32_bf16(fa[mi].v, fb[ni].v, acc[mi][ni], 0, 0, 0);
    }
  }
  #pragma unroll
  for (int mi = 0; mi < 2; ++mi)
    #pragma unroll
    for (int ni = 0; ni < 2; ++ni){
      const int n = nw + ni*16 + r;
      #pragma unroll
      for (int jr = 0; jr < 4; ++jr){
        size_t idx = (size_t)(m0 + mi*16 + q*4 + jr)*DM + n;
        out[idx] = acc[mi][ni][jr] + hbn[idx];
      }
    }
}

// ---------------- launch ----------------
extern "C" void kernel_launch(void* const* d_in, const int* in_sizes, int n_in,
                              void* d_out, int out_size, void* d_ws, size_t ws_size,
                              hipStream_t stream)
{
  const float* x      = (const float*)d_in[0];
  const float* adj    = (const float*)d_in[1];
  const float* w_gcn  = (const float*)d_in[2];
  const float* b_gcn  = (const float*)d_in[3];
  const float* gamma  = (const float*)d_in[4];
  const float* beta   = (const float*)d_in[5];
  const float* w_in   = (const float*)d_in[6];
  const float* conv_w = (const float*)d_in[7];
  const float* conv_b = (const float*)d_in[8];
  const float* w_xp   = (const float*)d_in[9];
  const float* w_dt   = (const float*)d_in[10];
  const float* b_dt   = (const float*)d_in[11];
  const float* A_log  = (const float*)d_in[12];
  const float* D_skip = (const float*)d_in[13];
  const float* w_out  = (const float*)d_in[14];
  float* out = (float*)d_out;
  char* ws = (char*)d_ws;
  if (ws_size < WS_NEED) return;

  unsigned short* xwT   = (unsigned short*)(ws + OFF_XWT);
  float*          h     = (float*)(ws + OFF_H);
  float*          hbn   = (float*)(ws + OFF_HBN);
  unsigned short* hbnb  = (unsigned short*)(ws + OFF_HBNB);
  unsigned short* winb  = (unsigned short*)(ws + OFF_WINB);
  unsigned short* wxpb  = (unsigned short*)(ws + OFF_WXPB);
  unsigned short* woutb = (unsigned short*)(ws + OFF_WOUTB);
  float*          xz    = (float*)(ws + OFF_XZ);
  float*          xc    = (float*)(ws + OFF_XC);
  unsigned short* xcb   = (unsigned short*)(ws + OFF_XCB);
  float*          xdbl  = (float*)(ws + OFF_XDBL);
  float*          dt    = (float*)(ws + OFF_DT);
  float*          Pm    = (float*)(ws + OFF_P);
  float*          Fm    = (float*)(ws + OFF_F);
  float*          Cy    = (float*)(ws + OFF_CARRY);
  unsigned short* yb    = (unsigned short*)(ws + OFF_YB);
  float*          bns   = (float*)(ws + OFF_BNS);
  float*          bns2  = (float*)(ws + OFF_BNS2);

  hipMemsetAsync(bns, 0, 2*256*sizeof(float), stream);   // bns and bns2 contiguous

  prep_kernel   <<<1024,  256, 0, stream>>>(w_in, w_xp, w_out, winb, wxpb, woutb);
  gemm1_kernel  <<<512,   256, 0, stream>>>(x, w_gcn, xwT);
  gemm2_kernel  <<<256,   512, 0, stream>>>(adj, xwT, b_gcn, h, bns, bns2);
  bnapply_kernel<<<8192,  256, 0, stream>>>(h, bns, bns2, gamma, beta, hbn, hbnb);
  gemm3_kernel  <<<1024,  256, 0, stream>>>(hbnb, winb, xz);
  conv_kernel   <<<16384, 256, 0, stream>>>(xz, conv_w, conv_b, xc, xcb);
  gemm4_kernel  <<<128,   256, 0, stream>>>(xcb, wxpb, xdbl);
  dt_kernel     <<<16384, 256, 0, stream>>>(xdbl, w_dt, b_dt, dt);
  scanA_kernel  <<<256,   256, 0, stream>>>(dt, xc, xdbl, A_log, Pm, Fm);
  scanB_kernel  <<<32,    256, 0, stream>>>(Pm, Fm, Cy);
  scanC_kernel  <<<256,   256, 0, stream>>>(dt, xc, xdbl, A_log, Cy, D_skip, xz, yb);
  gemm5_kernel  <<<256,   512, 0, stream>>>(yb, woutb, hbn, out);
}

// Round 2
// 629.777 us; speedup vs baseline: 1.1856x; 1.1856x over previous
//
#include <hip/hip_runtime.h>
#include <stdint.h>

#define NN   8192
#define FIN  128
#define DM   256
#define DI   512
#define DST  16
#define NC   256   // scan chunks
#define CL   32    // chunk length

typedef short bf16x8 __attribute__((ext_vector_type(8)));
typedef float f32x4 __attribute__((ext_vector_type(4)));
union FragU { unsigned u[4]; uint4 u4; bf16x8 v; };

__device__ __forceinline__ unsigned short f2bf(float x){
  unsigned u = __float_as_uint(x);
  return (unsigned short)((u + 0x7FFFu + ((u >> 16) & 1u)) >> 16);
}
__device__ __forceinline__ unsigned pack2(float a, float b){
  return (unsigned)f2bf(a) | ((unsigned)f2bf(b) << 16);
}
// fast round-to-nearest pack (add 0x8000, take hi16 of both via one v_perm)
__device__ __forceinline__ unsigned pack2rn(float a, float b){
  unsigned ua = __float_as_uint(a) + 0x8000u;
  unsigned ub = __float_as_uint(b) + 0x8000u;
  return __builtin_amdgcn_perm(ub, ua, 0x07060302u);
}
__device__ __forceinline__ float bf2f(unsigned short u){
  return __uint_as_float(((unsigned)u) << 16);
}
__device__ __forceinline__ float sigmoidf_(float x){ return 1.f / (1.f + __expf(-x)); }
__device__ __forceinline__ f32x4 zero4(){ f32x4 z; z[0]=0.f; z[1]=0.f; z[2]=0.f; z[3]=0.f; return z; }

#define ASYNC16(g, l) __builtin_amdgcn_global_load_lds( \
    (const __attribute__((address_space(1))) void*)(g), \
    (__attribute__((address_space(3))) void*)(l), 16, 0, 0)
#define WAITVM3  asm volatile("s_waitcnt vmcnt(3)" ::: "memory")
#define WAITVM0  asm volatile("s_waitcnt vmcnt(0)" ::: "memory")
#define WAITLGKM0 asm volatile("s_waitcnt lgkmcnt(0)" ::: "memory")
#define BARRIER  asm volatile("s_barrier" ::: "memory")

// ---------------- workspace layout ----------------
constexpr size_t OFF_XWT   = 0;                                  // xw^T bf16 [256][8192]
constexpr size_t OFF_HP    = OFF_XWT   + (size_t)DM*NN*2;        // gemm2 partials fp32 [2][8192][256]
constexpr size_t OFF_HB    = OFF_HP    + (size_t)2*NN*DM*4;      // relu(h) bf16
constexpr size_t OFF_HBNB  = OFF_HB    + (size_t)NN*DM*2;        // BN'd h bf16
constexpr size_t OFF_WINB  = OFF_HBNB  + (size_t)NN*DM*2;        // w_in bf16 [1024][256]
constexpr size_t OFF_WXPB  = OFF_WINB  + (size_t)1024*256*2;     // w_xproj bf16 [48][512]
constexpr size_t OFF_WOUTB = OFF_WXPB  + (size_t)48*512*2;       // w_out bf16 [256][512]
constexpr size_t OFF_XMB   = OFF_WOUTB + (size_t)256*512*2;      // xm bf16 [8192][512]
constexpr size_t OFF_ZB    = OFF_XMB   + (size_t)NN*DI*2;        // z bf16 [8192][512]
constexpr size_t OFF_XC    = OFF_ZB    + (size_t)NN*DI*2;        // xc fp32
constexpr size_t OFF_XCB   = OFF_XC    + (size_t)NN*DI*4;        // xc bf16
constexpr size_t OFF_XDBL  = OFF_XCB   + (size_t)NN*DI*2;        // x_dbl fp32 [8192][48]
constexpr size_t OFF_DT    = OFF_XDBL  + (size_t)NN*48*4;        // dt fp32 [8192][512]
constexpr size_t OFF_PF    = OFF_DT    + (size_t)NN*DI*4;        // chunk {P,F} float2 [256][8192]
constexpr size_t OFF_CY    = OFF_PF    + (size_t)NC*DI*DST*8;    // carry fp32 [256][8192]
constexpr size_t OFF_YB    = OFF_CY    + (size_t)NC*DI*DST*4;    // gated y bf16
constexpr size_t OFF_BNS   = OFF_YB    + (size_t)NN*DI*2;
constexpr size_t OFF_BNS2  = OFF_BNS   + 256*4;
constexpr size_t WS_NEED   = OFF_BNS2  + 256*4;

// ---------------- prep: fp32 -> bf16 weights ----------------
__global__ __launch_bounds__(256) void prep_kernel(
    const float* __restrict__ w_in, const float* __restrict__ w_xp, const float* __restrict__ w_out,
    unsigned short* __restrict__ o_in, unsigned short* __restrict__ o_xp, unsigned short* __restrict__ o_out)
{
  int i = blockIdx.x * 256 + threadIdx.x;
  if (i < 1024*256) o_in[i]  = f2bf(w_in[i]);
  if (i < 48*512)   o_xp[i]  = f2bf(w_xp[i]);
  if (i < 256*512)  o_out[i] = f2bf(w_out[i]);
}

// ---------------- gemm1: xw = x @ w_gcn, stored transposed bf16 [256][8192] ----------------
__global__ __launch_bounds__(256) void gemm1_kernel(
    const float* __restrict__ x, const float* __restrict__ w, unsigned short* __restrict__ xwT)
{
  __shared__ float xs[16*128];
  const int t = threadIdx.x;
  const int m0 = blockIdx.x * 16;
  {
    int r = t >> 4, c0 = (t & 15) * 8;
    const float* src = x + (size_t)(m0 + r)*FIN + c0;
    *(float4*)&xs[r*128 + c0]     = *(const float4*)src;
    *(float4*)&xs[r*128 + c0 + 4] = *(const float4*)(src + 4);
  }
  __syncthreads();
  const int n = t;
  float acc[16];
  #pragma unroll
  for (int m = 0; m < 16; ++m) acc[m] = 0.f;
  for (int k = 0; k < 128; k += 4){
    float w0 = w[(size_t)k*DM + n];
    float w1 = w[(size_t)(k+1)*DM + n];
    float w2 = w[(size_t)(k+2)*DM + n];
    float w3 = w[(size_t)(k+3)*DM + n];
    #pragma unroll
    for (int m = 0; m < 16; ++m){
      float4 xv = *(const float4*)&xs[m*128 + k];
      acc[m] = fmaf(xv.x, w0, acc[m]);
      acc[m] = fmaf(xv.y, w1, acc[m]);
      acc[m] = fmaf(xv.z, w2, acc[m]);
      acc[m] = fmaf(xv.w, w3, acc[m]);
    }
  }
  unsigned outp[8];
  #pragma unroll
  for (int m = 0; m < 8; ++m) outp[m] = pack2(acc[2*m], acc[2*m+1]);
  unsigned short* dst = xwT + (size_t)n*NN + m0;
  ((uint4*)dst)[0] = *(uint4*)&outp[0];
  ((uint4*)dst)[1] = *(uint4*)&outp[4];
}

// ---------------- gemm2: hp[ks] = adj[:, ks-half] @ xw[ks-half, :] ----------------
// M-tile 64, N full 256, K-split 2. BK=32. A (fp32) and B (bf16) both staged by
// global_load_lds into double-buffered LDS; raw s_barrier + manual vmcnt keeps
// the next DMA set in flight across barriers. XOR swizzle -> 2-way (free) LDS banks.
__global__ __launch_bounds__(512) void gemm2_kernel(
    const float* __restrict__ adj, const unsigned short* __restrict__ xwT,
    float* __restrict__ hp)
{
  __shared__ char lds[2][24576];   // per buffer: A fp32 [64][32] @0 (8KB), B bf16 256 rows x 32 @8192 (16KB)
  const int t = threadIdx.x;
  const int wave = t >> 6, lane = t & 63, r = lane & 15, q = lane >> 4;
  const int mt = (int)blockIdx.x & 127, ks = (int)blockIdx.x >> 7;
  const int m0 = mt * 64;
  const int kb = ks * 4096;
  const int wm = wave & 1, wn = wave >> 1;

  // A DMA: 1 issue (8KB): row = t>>3, dst group = t&7, src group = dstg ^ (row&7)
  const int arow = t >> 3;
  const int asg  = (t & 7) ^ (arow & 7);
  const float* asrc = adj + (size_t)(m0 + arow)*NN + kb + asg*4;
  const int adst = t * 16;
  // B DMA: 2 issues (16KB): nloc = si>>2, dstg = si&3, srcg = dstg ^ ((nloc>>1)&3)
  const int bn0 = t >> 2;
  const int bs0 = (t & 3) ^ ((bn0 >> 1) & 3);
  const int bn1 = (512 + t) >> 2;
  const int bs1 = ((512 + t) & 3) ^ ((bn1 >> 1) & 3);
  const unsigned short* bsrc0 = xwT + (size_t)bn0*NN + kb + bs0*8;
  const unsigned short* bsrc1 = xwT + (size_t)bn1*NN + kb + bs1*8;
  const int bdst0 = 8192 + t*16;
  const int bdst1 = 8192 + (512 + t)*16;

  f32x4 acc[2][4];
  #pragma unroll
  for (int mi = 0; mi < 2; ++mi)
    #pragma unroll
    for (int ni = 0; ni < 4; ++ni) acc[mi][ni] = zero4();

  // prologue: sets 0 and 1
  ASYNC16(asrc,       lds[0] + adst);
  ASYNC16(bsrc0,      lds[0] + bdst0);
  ASYNC16(bsrc1,      lds[0] + bdst1);
  ASYNC16(asrc + 32,  lds[1] + adst);
  ASYNC16(bsrc0 + 32, lds[1] + bdst0);
  ASYNC16(bsrc1 + 32, lds[1] + bdst1);

  // precomputed fragment offsets
  const int ar0 = wm*32 + r;
  const int ar1 = ar0 + 16;
  const int aoff00 = ar0*32 + (((2*q)   ^ (ar0 & 7)) << 2);
  const int aoff01 = ar0*32 + (((2*q+1) ^ (ar0 & 7)) << 2);
  const int aoff10 = ar1*32 + (((2*q)   ^ (ar1 & 7)) << 2);
  const int aoff11 = ar1*32 + (((2*q+1) ^ (ar1 & 7)) << 2);
  int boff[4];
  #pragma unroll
  for (int ni = 0; ni < 4; ++ni){
    int nl = wn*64 + ni*16 + r;
    boff[ni] = nl*4 + (q ^ ((nl >> 1) & 3));
  }

  #pragma unroll 2
  for (int k = 0; k < 128; ++k){
    if (k < 127) { WAITVM3; } else { WAITVM0; }
    BARRIER;
    const float* Af = (const float*)lds[k & 1];
    const uint4* Bf = (const uint4*)(lds[k & 1] + 8192);
    float4 p00 = *(const float4*)(Af + aoff00);
    float4 p01 = *(const float4*)(Af + aoff01);
    float4 p10 = *(const float4*)(Af + aoff10);
    float4 p11 = *(const float4*)(Af + aoff11);
    FragU fb[4];
    #pragma unroll
    for (int ni = 0; ni < 4; ++ni) fb[ni].u4 = Bf[boff[ni]];
    WAITLGKM0;
    BARRIER;
    if (k + 2 < 128){
      int k0 = (k + 2) * 32;
      char* L = lds[k & 1];
      ASYNC16(asrc + k0,  L + adst);
      ASYNC16(bsrc0 + k0, L + bdst0);
      ASYNC16(bsrc1 + k0, L + bdst1);
    }
    FragU fa0, fa1;
    fa0.u[0] = pack2rn(p00.x, p00.y); fa0.u[1] = pack2rn(p00.z, p00.w);
    fa0.u[2] = pack2rn(p01.x, p01.y); fa0.u[3] = pack2rn(p01.z, p01.w);
    fa1.u[0] = pack2rn(p10.x, p10.y); fa1.u[1] = pack2rn(p10.z, p10.w);
    fa1.u[2] = pack2rn(p11.x, p11.y); fa1.u[3] = pack2rn(p11.z, p11.w);
    #pragma unroll
    for (int ni = 0; ni < 4; ++ni){
      acc[0][ni] = __builtin_amdgcn_mfma_f32_16x16x32_bf16(fa0.v, fb[ni].v, acc[0][ni], 0, 0, 0);
      acc[1][ni] = __builtin_amdgcn_mfma_f32_16x16x32_bf16(fa1.v, fb[ni].v, acc[1][ni], 0, 0, 0);
    }
  }

  float* hpo = hp + (size_t)ks * ((size_t)NN * DM);
  #pragma unroll
  for (int mi = 0; mi < 2; ++mi)
    #pragma unroll
    for (int ni = 0; ni < 4; ++ni){
      const int n = wn*64 + ni*16 + r;
      #pragma unroll
      for (int jr = 0; jr < 4; ++jr){
        const int m = m0 + wm*32 + mi*16 + q*4 + jr;
        hpo[(size_t)m*DM + n] = acc[mi][ni][jr];
      }
    }
}

// ---------------- hred: h = relu(hp0+hp1+bias) -> bf16, + BN stats atomics ----------------
__global__ __launch_bounds__(256) void hred_kernel(
    const float* __restrict__ hp, const float* __restrict__ b_gcn,
    unsigned short* __restrict__ hb, float* __restrict__ bns, float* __restrict__ bns2)
{
  const int c = threadIdx.x;
  const int m0 = blockIdx.x * 32;
  const float bias = b_gcn[c];
  float s1 = 0.f, s2 = 0.f;
  #pragma unroll 8
  for (int rr = 0; rr < 32; ++rr){
    size_t idx = (size_t)(m0 + rr)*DM + c;
    float v = hp[idx] + hp[(size_t)NN*DM + idx] + bias;
    v = fmaxf(v, 0.f);
    hb[idx] = f2bf(v);
    s1 += v; s2 += v*v;
  }
  atomicAdd(bns + c, s1);
  atomicAdd(bns2 + c, s2);
}

// ---------------- bnapply: hbnb = BN(hb) bf16 ----------------
__global__ __launch_bounds__(256) void bnapply_kernel(
    const unsigned short* __restrict__ hb, const float* __restrict__ s1, const float* __restrict__ s2,
    const float* __restrict__ gamma, const float* __restrict__ beta,
    unsigned short* __restrict__ hbnb)
{
  int base = (blockIdx.x*256 + threadIdx.x) * 2;
  int c0 = base & (DM - 1);
  ushort2 hv = *(const ushort2*)(hb + base);
  float mA = s1[c0] * (1.f/NN),   mB = s1[c0+1] * (1.f/NN);
  float vA = s2[c0] * (1.f/NN) - mA*mA, vB = s2[c0+1] * (1.f/NN) - mB*mB;
  float iA = rsqrtf(vA + 1e-5f), iB = rsqrtf(vB + 1e-5f);
  float a = (bf2f(hv.x) - mA)*iA*gamma[c0]   + beta[c0];
  float b = (bf2f(hv.y) - mB)*iB*gamma[c0+1] + beta[c0+1];
  ushort2 o; o.x = f2bf(a); o.y = f2bf(b);
  *(ushort2*)(hbnb + base) = o;
}

// ---------------- gemm3: [xm|z] = hbnb @ w_in^T (M=8192,K=256,N=1024), bf16 out ----------------
__global__ __launch_bounds__(256) void gemm3_kernel(
    const unsigned short* __restrict__ Ab, const unsigned short* __restrict__ Wb,
    unsigned short* __restrict__ xmb, unsigned short* __restrict__ zb)
{
  __shared__ uint4 alds[2048];  // 64 rows x 32 slots (swizzled), 32 KB
  const int t = threadIdx.x;
  const int wave = t >> 6, lane = t & 63, r = lane & 15, q = lane >> 4;
  const int mb = ((int)blockIdx.x & 127) * 64;
  const int nb = ((int)blockIdx.x >> 7) * 128;
  const int wm = wave & 1, wn = wave >> 1;

  #pragma unroll
  for (int j = 0; j < 8; ++j){
    int si = j*256 + t;
    int row = si >> 5, dg = si & 31;
    int sg = dg ^ (row & 31);
    ASYNC16(Ab + (size_t)(mb + row)*DM + sg*8, (char*)alds + si*16);
  }
  __syncthreads();

  f32x4 acc[2][4];
  #pragma unroll
  for (int mi = 0; mi < 2; ++mi)
    #pragma unroll
    for (int ni = 0; ni < 4; ++ni) acc[mi][ni] = zero4();

  const unsigned short* bp[4];
  #pragma unroll
  for (int ni = 0; ni < 4; ++ni)
    bp[ni] = Wb + (size_t)(nb + wn*64 + ni*16 + r)*DM + q*8;
  FragU fb[4];
  #pragma unroll
  for (int ni = 0; ni < 4; ++ni) fb[ni].u4 = *(const uint4*)bp[ni];

  #pragma unroll
  for (int it = 0; it < 8; ++it){
    FragU fbn[4];
    if (it < 7){
      #pragma unroll
      for (int ni = 0; ni < 4; ++ni) fbn[ni].u4 = *(const uint4*)(bp[ni] + (it+1)*32);
    }
    FragU fa[2];
    #pragma unroll
    for (int mi = 0; mi < 2; ++mi){
      int row = wm*32 + mi*16 + r;
      int g = it*4 + q;
      fa[mi].u4 = alds[row*32 + (g ^ (row & 31))];
    }
    #pragma unroll
    for (int mi = 0; mi < 2; ++mi)
      #pragma unroll
      for (int ni = 0; ni < 4; ++ni)
        acc[mi][ni] = __builtin_amdgcn_mfma_f32_16x16x32_bf16(fa[mi].v, fb[ni].v, acc[mi][ni], 0, 0, 0);
    if (it < 7){
      #pragma unroll
      for (int ni = 0; ni < 4; ++ni) fb[ni] = fbn[ni];
    }
  }
  #pragma unroll
  for (int mi = 0; mi < 2; ++mi)
    #pragma unroll
    for (int ni = 0; ni < 4; ++ni){
      int nc = nb + wn*64 + ni*16 + r;
      unsigned short* dst = (nc < 512) ? (xmb + nc) : (zb + (nc - 512));
      #pragma unroll
      for (int jr = 0; jr < 4; ++jr){
        int m = mb + wm*32 + mi*16 + q*4 + jr;
        dst[(size_t)m*DI] = f2bf(acc[mi][ni][jr]);
      }
    }
}

// ---------------- conv: depthwise causal D=4 + SiLU, register row-window ----------------
__global__ __launch_bounds__(256) void conv_kernel(
    const unsigned short* __restrict__ xmb, const float* __restrict__ conv_w, const float* __restrict__ conv_b,
    float* __restrict__ xc, unsigned short* __restrict__ xcb)
{
  const int d0 = threadIdx.x * 2;
  const int n0 = blockIdx.x * 32;
  float4 wa = *(const float4*)(conv_w + (size_t)d0*4);
  float4 wb = *(const float4*)(conv_w + (size_t)d0*4 + 4);
  float2 bias = *(const float2*)(conv_b + d0);
  float x0a=0.f,x1a=0.f,x2a=0.f, x0b=0.f,x1b=0.f,x2b=0.f;
  #pragma unroll
  for (int j = 0; j < 3; ++j){
    int n = n0 - 3 + j;
    float va = 0.f, vb = 0.f;
    if (n >= 0){
      ushort2 u = *(const ushort2*)(xmb + (size_t)n*DI + d0);
      va = bf2f(u.x); vb = bf2f(u.y);
    }
    if (j == 0){ x0a = va; x0b = vb; }
    else if (j == 1){ x1a = va; x1b = vb; }
    else { x2a = va; x2b = vb; }
  }
  for (int j = 0; j < 32; ++j){
    int n = n0 + j;
    ushort2 u = *(const ushort2*)(xmb + (size_t)n*DI + d0);
    float x3a = bf2f(u.x), x3b = bf2f(u.y);
    float sa = bias.x + wa.x*x0a + wa.y*x1a + wa.z*x2a + wa.w*x3a;
    float sb = bias.y + wb.x*x0b + wb.y*x1b + wb.z*x2b + wb.w*x3b;
    float va = sa * sigmoidf_(sa);
    float vb = sb * sigmoidf_(sb);
    *(float2*)(xc + (size_t)n*DI + d0) = make_float2(va, vb);
    ushort2 o; o.x = f2bf(va); o.y = f2bf(vb);
    *(ushort2*)(xcb + (size_t)n*DI + d0) = o;
    x0a=x1a; x1a=x2a; x2a=x3a;
    x0b=x1b; x1b=x2b; x2b=x3b;
  }
}

// ---------------- gemm4: x_dbl = xc @ w_xproj^T (M=8192,K=512,N=48) ----------------
// M-tile 32, whole K staged via DMA; 4 waves split K, LDS cross-wave reduce.
__global__ __launch_bounds__(256) void gemm4_kernel(
    const unsigned short* __restrict__ Ab, const unsigned short* __restrict__ Wb, float* __restrict__ xdbl)
{
  __shared__ uint4 alds[2048];  // 32 rows x 64 slots, 32 KB
  const int t = threadIdx.x;
  const int wave = t >> 6, lane = t & 63, r = lane & 15, q = lane >> 4;
  const int m0 = (int)blockIdx.x * 32;
  #pragma unroll
  for (int j = 0; j < 8; ++j){
    int si = j*256 + t;
    int row = si >> 6, dg = si & 63;
    int sg = dg ^ (row & 31);
    ASYNC16(Ab + (size_t)(m0 + row)*DI + sg*8, (char*)alds + si*16);
  }
  __syncthreads();
  f32x4 acc[2][3];
  #pragma unroll
  for (int mi = 0; mi < 2; ++mi)
    #pragma unroll
    for (int ni = 0; ni < 3; ++ni) acc[mi][ni] = zero4();
  const int kq = wave * 128;
  const unsigned short* bp[3];
  #pragma unroll
  for (int ni = 0; ni < 3; ++ni) bp[ni] = Wb + (size_t)(ni*16 + r)*DI + kq + q*8;
  FragU fb[3];
  #pragma unroll
  for (int ni = 0; ni < 3; ++ni) fb[ni].u4 = *(const uint4*)bp[ni];
  #pragma unroll
  for (int it = 0; it < 4; ++it){
    FragU fbn[3];
    if (it < 3){
      #pragma unroll
      for (int ni = 0; ni < 3; ++ni) fbn[ni].u4 = *(const uint4*)(bp[ni] + (it+1)*32);
    }
    FragU fa[2];
    #pragma unroll
    for (int mi = 0; mi < 2; ++mi){
      int row = mi*16 + r;
      int g = (kq >> 3) + it*4 + q;
      fa[mi].u4 = alds[row*64 + (g ^ (row & 31))];
    }
    #pragma unroll
    for (int mi = 0; mi < 2; ++mi)
      #pragma unroll
      for (int ni = 0; ni < 3; ++ni)
        acc[mi][ni] = __builtin_amdgcn_mfma_f32_16x16x32_bf16(fa[mi].v, fb[ni].v, acc[mi][ni], 0, 0, 0);
    if (it < 3){
      #pragma unroll
      for (int ni = 0; ni < 3; ++ni) fb[ni] = fbn[ni];
    }
  }
  __syncthreads();
  float* red = (float*)alds;
  if (wave > 0){
    int base = ((wave - 1)*64 + lane)*24;
    #pragma unroll
    for (int mi = 0; mi < 2; ++mi)
      #pragma unroll
      for (int ni = 0; ni < 3; ++ni)
        #pragma unroll
        for (int jr = 0; jr < 4; ++jr)
          red[base + (mi*3 + ni)*4 + jr] = acc[mi][ni][jr];
  }
  __syncthreads();
  if (wave == 0){
    #pragma unroll
    for (int w = 0; w < 3; ++w){
      int base = (w*64 + lane)*24;
      #pragma unroll
      for (int mi = 0; mi < 2; ++mi)
        #pragma unroll
        for (int ni = 0; ni < 3; ++ni)
          #pragma unroll
          for (int jr = 0; jr < 4; ++jr)
            acc[mi][ni][jr] += red[base + (mi*3 + ni)*4 + jr];
    }
    #pragma unroll
    for (int mi = 0; mi < 2; ++mi)
      #pragma unroll
      for (int ni = 0; ni < 3; ++ni)
        #pragma unroll
        for (int jr = 0; jr < 4; ++jr)
          xdbl[(size_t)(m0 + mi*16 + q*4 + jr)*48 + ni*16 + r] = acc[mi][ni][jr];
  }
}

// ---------------- dt = softplus(dt_r @ w_dt^T + b_dt), 64-row strips ----------------
__global__ __launch_bounds__(256) void dt_kernel(
    const float* __restrict__ xdbl, const float* __restrict__ w_dt, const float* __restrict__ b_dt,
    float* __restrict__ dt)
{
  __shared__ float xr[64*16];
  const int t = threadIdx.x;
  const int dg = (int)blockIdx.x & 1;
  const int n0 = ((int)blockIdx.x >> 1) * 64;
  const int d = dg*256 + t;
  #pragma unroll
  for (int j = 0; j < 4; ++j){
    int idx = t + 256*j;
    xr[idx] = xdbl[(size_t)(n0 + (idx >> 4))*48 + (idx & 15)];
  }
  __syncthreads();
  const float4* wp = (const float4*)(w_dt + (size_t)d*16);
  float4 w0 = wp[0], w1 = wp[1], w2 = wp[2], w3 = wp[3];
  float bias = b_dt[d];
  for (int j = 0; j < 64; ++j){
    const float4* xp = (const float4*)(xr + j*16);
    float4 a0 = xp[0], a1 = xp[1], a2 = xp[2], a3 = xp[3];
    float a = bias;
    a += w0.x*a0.x + w0.y*a0.y + w0.z*a0.z + w0.w*a0.w;
    a += w1.x*a1.x + w1.y*a1.y + w1.z*a1.z + w1.w*a1.w;
    a += w2.x*a2.x + w2.y*a2.y + w2.z*a2.z + w2.w*a2.w;
    a += w3.x*a3.x + w3.y*a3.y + w3.z*a3.z + w3.w*a3.w;
    float o = (a > 20.f) ? a : log1pf(__expf(a));
    dt[(size_t)(n0 + j)*DI + d] = o;
  }
}

// ---------------- scanA: per-chunk local recurrence -> interleaved {P,F} ----------------
__global__ __launch_bounds__(256) void scanA_kernel(
    const float* __restrict__ dt, const float* __restrict__ xc,
    const float* __restrict__ xdbl, const float* __restrict__ A_log,
    float2* __restrict__ PF)
{
  __shared__ float Bs[CL*DST];
  const int t = threadIdx.x;
  const int c = (int)blockIdx.x >> 1;
  const int d = (((int)blockIdx.x & 1) << 8) + t;
  #pragma unroll
  for (int j = 0; j < 2; ++j){
    int idx = t + 256*j;
    Bs[idx] = xdbl[(size_t)(c*CL + (idx >> 4))*48 + 16 + (idx & 15)];
  }
  __syncthreads();
  float Av[DST], hs[DST];
  {
    const float4* Ap = (const float4*)(A_log + (size_t)d*DST);
    #pragma unroll
    for (int s4 = 0; s4 < 4; ++s4){
      float4 a4 = Ap[s4];
      Av[s4*4+0] = -__expf(a4.x); Av[s4*4+1] = -__expf(a4.y);
      Av[s4*4+2] = -__expf(a4.z); Av[s4*4+3] = -__expf(a4.w);
    }
  }
  #pragma unroll
  for (int s = 0; s < DST; ++s) hs[s] = 0.f;
  float sdt = 0.f;
  const size_t rb = (size_t)c*CL*DI + d;
  float dtv = dt[rb], xcv = xc[rb];
  for (int tt = 0; tt < CL; ++tt){
    float dtn = 0.f, xcn = 0.f;
    if (tt + 1 < CL){
      dtn = dt[rb + (size_t)(tt+1)*DI];
      xcn = xc[rb + (size_t)(tt+1)*DI];
    }
    float u = dtv * xcv;
    sdt += dtv;
    float bv[DST];
    *(float4*)&bv[0]  = *(const float4*)&Bs[tt*16];
    *(float4*)&bv[4]  = *(const float4*)&Bs[tt*16 + 4];
    *(float4*)&bv[8]  = *(const float4*)&Bs[tt*16 + 8];
    *(float4*)&bv[12] = *(const float4*)&Bs[tt*16 + 12];
    #pragma unroll
    for (int s = 0; s < DST; ++s)
      hs[s] = __expf(dtv * Av[s]) * hs[s] + u * bv[s];
    dtv = dtn; xcv = xcn;
  }
  float4* out = (float4*)(PF + (size_t)c*(DI*DST) + (size_t)d*DST);
  #pragma unroll
  for (int j = 0; j < 8; ++j){
    float4 v;
    v.x = __expf(Av[2*j] * sdt);   v.y = hs[2*j];
    v.z = __expf(Av[2*j+1] * sdt); v.w = hs[2*j+1];
    out[j] = v;
  }
}

// ---------------- scanB: sequential carry across 256 chunks, batched prefetch ----------------
__global__ __launch_bounds__(128) void scanB_kernel(
    const float2* __restrict__ PF, float* __restrict__ Cy)
{
  const int ds = (int)blockIdx.x*128 + (int)threadIdx.x;
  float2 A0[16], A1[16];
  #pragma unroll
  for (int j = 0; j < 16; ++j) A0[j] = PF[(size_t)j*8192 + ds];
  #pragma unroll
  for (int j = 0; j < 16; ++j) A1[j] = PF[(size_t)(16 + j)*8192 + ds];
  float cy = 0.f;
  Cy[ds] = 0.f;
  #pragma unroll
  for (int g = 0; g < 16; ++g){
    #pragma unroll
    for (int j = 0; j < 16; ++j){
      int i = g*16 + j;
      if (i < NC - 1){
        float2 pf = (g & 1) ? A1[j] : A0[j];
        cy = pf.x * cy + pf.y;
        Cy[(size_t)(i + 1)*8192 + ds] = cy;
      }
    }
    int gn = g + 2;
    if (gn < 16){
      #pragma unroll
      for (int j = 0; j < 16; ++j){
        float2 v = PF[(size_t)(gn*16 + j)*8192 + ds];
        if (g & 1) A1[j] = v; else A0[j] = v;
      }
    }
  }
}

// ---------------- scanC: recompute with carry, emit gated y (bf16) ----------------
__global__ __launch_bounds__(256) void scanC_kernel(
    const float* __restrict__ dt, const float* __restrict__ xc,
    const float* __restrict__ xdbl, const float* __restrict__ A_log,
    const float* __restrict__ Cy, const float* __restrict__ Dskip,
    const unsigned short* __restrict__ zb, unsigned short* __restrict__ yb)
{
  __shared__ float Bs[CL*DST];
  __shared__ float Cs[CL*DST];
  const int t = threadIdx.x;
  const int c = (int)blockIdx.x >> 1;
  const int d = (((int)blockIdx.x & 1) << 8) + t;
  #pragma unroll
  for (int j = 0; j < 2; ++j){
    int idx = t + 256*j;
    int tg = c*CL + (idx >> 4);
    Bs[idx] = xdbl[(size_t)tg*48 + 16 + (idx & 15)];
    Cs[idx] = xdbl[(size_t)tg*48 + 32 + (idx & 15)];
  }
  __syncthreads();
  float Av[DST], hs[DST];
  {
    const float4* Ap = (const float4*)(A_log + (size_t)d*DST);
    #pragma unroll
    for (int s4 = 0; s4 < 4; ++s4){
      float4 a4 = Ap[s4];
      Av[s4*4+0] = -__expf(a4.x); Av[s4*4+1] = -__expf(a4.y);
      Av[s4*4+2] = -__expf(a4.z); Av[s4*4+3] = -__expf(a4.w);
    }
  }
  {
    const float4* hp4 = (const float4*)(Cy + (size_t)c*(DI*DST) + (size_t)d*DST);
    #pragma unroll
    for (int s4 = 0; s4 < 4; ++s4){
      float4 h4 = hp4[s4];
      hs[s4*4+0] = h4.x; hs[s4*4+1] = h4.y; hs[s4*4+2] = h4.z; hs[s4*4+3] = h4.w;
    }
  }
  const float Dv = Dskip[d];
  const size_t rb = (size_t)c*CL*DI + d;
  float dtv = dt[rb], xcv = xc[rb];
  unsigned short zv0 = zb[rb];
  for (int tt = 0; tt < CL; ++tt){
    float dtn = 0.f, xcn = 0.f;
    unsigned short zn = 0;
    if (tt + 1 < CL){
      dtn = dt[rb + (size_t)(tt+1)*DI];
      xcn = xc[rb + (size_t)(tt+1)*DI];
      zn  = zb[rb + (size_t)(tt+1)*DI];
    }
    float u = dtv * xcv;
    float bv[DST], cv[DST];
    *(float4*)&bv[0]  = *(const float4*)&Bs[tt*16];
    *(float4*)&bv[4]  = *(const float4*)&Bs[tt*16 + 4];
    *(float4*)&bv[8]  = *(const float4*)&Bs[tt*16 + 8];
    *(float4*)&bv[12] = *(const float4*)&Bs[tt*16 + 12];
    *(float4*)&cv[0]  = *(const float4*)&Cs[tt*16];
    *(float4*)&cv[4]  = *(const float4*)&Cs[tt*16 + 4];
    *(float4*)&cv[8]  = *(const float4*)&Cs[tt*16 + 8];
    *(float4*)&cv[12] = *(const float4*)&Cs[tt*16 + 12];
    float y0 = 0.f, y1 = 0.f;
    #pragma unroll
    for (int s = 0; s < DST; s += 2){
      hs[s]   = __expf(dtv * Av[s])   * hs[s]   + u * bv[s];
      hs[s+1] = __expf(dtv * Av[s+1]) * hs[s+1] + u * bv[s+1];
      y0 += hs[s]   * cv[s];
      y1 += hs[s+1] * cv[s+1];
    }
    float z = bf2f(zv0);
    float yf = ((y0 + y1) + Dv * xcv) * (z * sigmoidf_(z));
    yb[rb + (size_t)tt*DI] = f2bf(yf);
    dtv = dtn; xcv = xcn; zv0 = zn;
  }
}

// ---------------- gemm5: out = y @ w_out^T + hbn (M=8192,K=512,N=256) ----------------
__global__ __launch_bounds__(512) void gemm5_kernel(
    const unsigned short* __restrict__ yb, const unsigned short* __restrict__ Wb,
    const unsigned short* __restrict__ hbnb, float* __restrict__ out)
{
  __shared__ uint4 alds[2048];  // 32 rows x 64 slots, 32 KB
  const int t = threadIdx.x;
  const int wave = t >> 6, lane = t & 63, r = lane & 15, q = lane >> 4;
  const int m0 = (int)blockIdx.x * 32;
  #pragma unroll
  for (int j = 0; j < 4; ++j){
    int si = j*512 + t;
    int row = si >> 6, dg = si & 63;
    int sg = dg ^ (row & 31);
    ASYNC16(yb + (size_t)(m0 + row)*DI + sg*8, (char*)alds + si*16);
  }
  __syncthreads();
  f32x4 acc[2][2];
  #pragma unroll
  for (int mi = 0; mi < 2; ++mi)
    #pragma unroll
    for (int ni = 0; ni < 2; ++ni) acc[mi][ni] = zero4();
  const int nw = wave * 32;
  const unsigned short* bp0 = Wb + (size_t)(nw + r)*DI + q*8;
  const unsigned short* bp1 = Wb + (size_t)(nw + 16 + r)*DI + q*8;
  FragU fb0, fb1;
  fb0.u4 = *(const uint4*)bp0;
  fb1.u4 = *(const uint4*)bp1;
  #pragma unroll
  for (int it = 0; it < 16; ++it){
    FragU fn0, fn1;
    if (it < 15){
      fn0.u4 = *(const uint4*)(bp0 + (it+1)*32);
      fn1.u4 = *(const uint4*)(bp1 + (it+1)*32);
    }
    FragU fa[2];
    #pragma unroll
    for (int mi = 0; mi < 2; ++mi){
      int row = mi*16 + r;
      int g = it*4 + q;
      fa[mi].u4 = alds[row*64 + (g ^ (row & 31))];
    }
    acc[0][0] = __builtin_amdgcn_mfma_f32_16x16x32_bf16(fa[0].v, fb0.v, acc[0][0], 0, 0, 0);
    acc[0][1] = __builtin_amdgcn_mfma_f32_16x16x32_bf16(fa[0].v, fb1.v, acc[0][1], 0, 0, 0);
    acc[1][0] = __builtin_amdgcn_mfma_f32_16x16x32_bf16(fa[1].v, fb0.v, acc[1][0], 0, 0, 0);
    acc[1][1] = __builtin_amdgcn_mfma_f32_16x16x32_bf16(fa[1].v, fb1.v, acc[1][1], 0, 0, 0);
    if (it < 15){ fb0 = fn0; fb1 = fn1; }
  }
  #pragma unroll
  for (int mi = 0; mi < 2; ++mi)
    #pragma unroll
    for (int ni = 0; ni < 2; ++ni){
      const int n = nw + ni*16 + r;
      #pragma unroll
      for (int jr = 0; jr < 4; ++jr){
        const int m = m0 + mi*16 + q*4 + jr;
        size_t idx = (size_t)m*DM + n;
        out[idx] = acc[mi][ni][jr] + bf2f(hbnb[idx]);
      }
    }
}

// ---------------- launch ----------------
extern "C" void kernel_launch(void* const* d_in, const int* in_sizes, int n_in,
                              void* d_out, int out_size, void* d_ws, size_t ws_size,
                              hipStream_t stream)
{
  const float* x      = (const float*)d_in[0];
  const float* adj    = (const float*)d_in[1];
  const float* w_gcn  = (const float*)d_in[2];
  const float* b_gcn  = (const float*)d_in[3];
  const float* gamma  = (const float*)d_in[4];
  const float* beta   = (const float*)d_in[5];
  const float* w_in   = (const float*)d_in[6];
  const float* conv_w = (const float*)d_in[7];
  const float* conv_b = (const float*)d_in[8];
  const float* w_xp   = (const float*)d_in[9];
  const float* w_dt   = (const float*)d_in[10];
  const float* b_dt   = (const float*)d_in[11];
  const float* A_log  = (const float*)d_in[12];
  const float* D_skip = (const float*)d_in[13];
  const float* w_out  = (const float*)d_in[14];
  float* out = (float*)d_out;
  char* ws = (char*)d_ws;
  if (ws_size < WS_NEED) return;

  unsigned short* xwT   = (unsigned short*)(ws + OFF_XWT);
  float*          hp    = (float*)(ws + OFF_HP);
  unsigned short* hb    = (unsigned short*)(ws + OFF_HB);
  unsigned short* hbnb  = (unsigned short*)(ws + OFF_HBNB);
  unsigned short* winb  = (unsigned short*)(ws + OFF_WINB);
  unsigned short* wxpb  = (unsigned short*)(ws + OFF_WXPB);
  unsigned short* woutb = (unsigned short*)(ws + OFF_WOUTB);
  unsigned short* xmb   = (unsigned short*)(ws + OFF_XMB);
  unsigned short* zb    = (unsigned short*)(ws + OFF_ZB);
  float*          xc    = (float*)(ws + OFF_XC);
  unsigned short* xcb   = (unsigned short*)(ws + OFF_XCB);
  float*          xdbl  = (float*)(ws + OFF_XDBL);
  float*          dtb   = (float*)(ws + OFF_DT);
  float2*         PF    = (float2*)(ws + OFF_PF);
  float*          Cy    = (float*)(ws + OFF_CY);
  unsigned short* yb    = (unsigned short*)(ws + OFF_YB);
  float*          bns   = (float*)(ws + OFF_BNS);
  float*          bns2  = (float*)(ws + OFF_BNS2);

  hipMemsetAsync(bns, 0, 2*256*sizeof(float), stream);

  prep_kernel   <<<1024, 256, 0, stream>>>(w_in, w_xp, w_out, winb, wxpb, woutb);
  gemm1_kernel  <<<512,  256, 0, stream>>>(x, w_gcn, xwT);
  gemm2_kernel  <<<256,  512, 0, stream>>>(adj, xwT, hp);
  hred_kernel   <<<256,  256, 0, stream>>>(hp, b_gcn, hb, bns, bns2);
  bnapply_kernel<<<4096, 256, 0, stream>>>(hb, bns, bns2, gamma, beta, hbnb);
  gemm3_kernel  <<<1024, 256, 0, stream>>>(hbnb, winb, xmb, zb);
  conv_kernel   <<<256,  256, 0, stream>>>(xmb, conv_w, conv_b, xc, xcb);
  gemm4_kernel  <<<256,  256, 0, stream>>>(xcb, wxpb, xdbl);
  dt_kernel     <<<256,  256, 0, stream>>>(xdbl, w_dt, b_dt, dtb);
  scanA_kernel  <<<512,  256, 0, stream>>>(dtb, xc, xdbl, A_log, PF);
  scanB_kernel  <<<64,   128, 0, stream>>>(PF, Cy);
  scanC_kernel  <<<512,  256, 0, stream>>>(dtb, xc, xdbl, A_log, Cy, D_skip, zb, yb);
  gemm5_kernel  <<<256,  512, 0, stream>>>(yb, woutb, hbnb, out);
}

// Round 3
// 598.046 us; speedup vs baseline: 1.2485x; 1.0531x over previous
//
#include <hip/hip_runtime.h>
#include <stdint.h>

#define NN   8192
#define FIN  128
#define DM   256
#define DI   512
#define DST  16
#define NC   256   // scan chunks
#define CL   32    // chunk length

typedef short bf16x8 __attribute__((ext_vector_type(8)));
typedef float f32x4 __attribute__((ext_vector_type(4)));
union FragU { unsigned u[4]; uint4 u4; bf16x8 v; };

__device__ __forceinline__ unsigned short f2bf(float x){
  unsigned u = __float_as_uint(x);
  return (unsigned short)((u + 0x7FFFu + ((u >> 16) & 1u)) >> 16);
}
__device__ __forceinline__ unsigned pack2(float a, float b){
  return (unsigned)f2bf(a) | ((unsigned)f2bf(b) << 16);
}
// fast round-to-nearest pack (one v_perm for hi16 of both)
__device__ __forceinline__ unsigned pack2rn(float a, float b){
  unsigned ua = __float_as_uint(a) + 0x8000u;
  unsigned ub = __float_as_uint(b) + 0x8000u;
  return __builtin_amdgcn_perm(ub, ua, 0x07060302u);
}
__device__ __forceinline__ float bf2f(unsigned short u){
  return __uint_as_float(((unsigned)u) << 16);
}
__device__ __forceinline__ float sigmoidf_(float x){ return 1.f / (1.f + __expf(-x)); }
__device__ __forceinline__ f32x4 zero4(){ f32x4 z; z[0]=0.f; z[1]=0.f; z[2]=0.f; z[3]=0.f; return z; }

#define ASYNC16(g, l) __builtin_amdgcn_global_load_lds( \
    (const __attribute__((address_space(1))) void*)(g), \
    (__attribute__((address_space(3))) void*)(l), 16, 0, 0)
#define WAITVM8  asm volatile("s_waitcnt vmcnt(8)" ::: "memory")
#define WAITVM4  asm volatile("s_waitcnt vmcnt(4)" ::: "memory")
#define WAITVM3  asm volatile("s_waitcnt vmcnt(3)" ::: "memory")
#define WAITVM0  asm volatile("s_waitcnt vmcnt(0)" ::: "memory")
#define WAITLGKM0 asm volatile("s_waitcnt lgkmcnt(0)" ::: "memory")
#define BARRIER  asm volatile("s_barrier" ::: "memory")

// ---------------- workspace layout ----------------
constexpr size_t OFF_XWT   = 0;                                  // xw^T bf16 [256][8192]
constexpr size_t OFF_HB    = OFF_XWT   + (size_t)DM*NN*2;        // relu(h) bf16
constexpr size_t OFF_HBNB  = OFF_HB    + (size_t)NN*DM*2;        // BN'd h bf16
constexpr size_t OFF_WINB  = OFF_HBNB  + (size_t)NN*DM*2;        // w_in bf16 [1024][256]
constexpr size_t OFF_WXPB  = OFF_WINB  + (size_t)1024*256*2;     // w_xproj bf16 [48][512]
constexpr size_t OFF_WOUTB = OFF_WXPB  + (size_t)48*512*2;       // w_out bf16 [256][512]
constexpr size_t OFF_XMB   = OFF_WOUTB + (size_t)256*512*2;      // xm bf16 [8192][512]
constexpr size_t OFF_ZB    = OFF_XMB   + (size_t)NN*DI*2;        // z bf16 [8192][512]
constexpr size_t OFF_XC    = OFF_ZB    + (size_t)NN*DI*2;        // xc fp32
constexpr size_t OFF_XCB   = OFF_XC    + (size_t)NN*DI*4;        // xc bf16
constexpr size_t OFF_XDBL  = OFF_XCB   + (size_t)NN*DI*2;        // x_dbl fp32 [8192][48]
constexpr size_t OFF_DT    = OFF_XDBL  + (size_t)NN*48*4;        // dt fp32 [8192][512]
constexpr size_t OFF_PF    = OFF_DT    + (size_t)NN*DI*4;        // chunk {P,F} float2 [256][8192]
constexpr size_t OFF_CY    = OFF_PF    + (size_t)NC*DI*DST*8;    // carry fp32 [256][8192]
constexpr size_t OFF_YB    = OFF_CY    + (size_t)NC*DI*DST*4;    // gated y bf16
constexpr size_t OFF_BNS   = OFF_YB    + (size_t)NN*DI*2;
constexpr size_t OFF_BNS2  = OFF_BNS   + 256*4;
constexpr size_t WS_NEED   = OFF_BNS2  + 256*4;
// gemm2 fp32 partials [4][8192][256] = 32MB alias onto PF+CY+YB (dead until scanA)
constexpr size_t OFF_HP    = OFF_PF;

// ---------------- prep: fp32 -> bf16 weights ----------------
__global__ __launch_bounds__(256) void prep_kernel(
    const float* __restrict__ w_in, const float* __restrict__ w_xp, const float* __restrict__ w_out,
    unsigned short* __restrict__ o_in, unsigned short* __restrict__ o_xp, unsigned short* __restrict__ o_out)
{
  int i = blockIdx.x * 256 + threadIdx.x;
  if (i < 1024*256) o_in[i]  = f2bf(w_in[i]);
  if (i < 48*512)   o_xp[i]  = f2bf(w_xp[i]);
  if (i < 256*512)  o_out[i] = f2bf(w_out[i]);
}

// ---------------- gemm1: xw = x @ w_gcn, stored transposed bf16 [256][8192] ----------------
__global__ __launch_bounds__(256) void gemm1_kernel(
    const float* __restrict__ x, const float* __restrict__ w, unsigned short* __restrict__ xwT)
{
  __shared__ float xs[16*128];
  const int t = threadIdx.x;
  const int m0 = blockIdx.x * 16;
  {
    int r = t >> 4, c0 = (t & 15) * 8;
    const float* src = x + (size_t)(m0 + r)*FIN + c0;
    *(float4*)&xs[r*128 + c0]     = *(const float4*)src;
    *(float4*)&xs[r*128 + c0 + 4] = *(const float4*)(src + 4);
  }
  __syncthreads();
  const int n = t;
  float acc[16];
  #pragma unroll
  for (int m = 0; m < 16; ++m) acc[m] = 0.f;
  for (int k = 0; k < 128; k += 4){
    float w0 = w[(size_t)k*DM + n];
    float w1 = w[(size_t)(k+1)*DM + n];
    float w2 = w[(size_t)(k+2)*DM + n];
    float w3 = w[(size_t)(k+3)*DM + n];
    #pragma unroll
    for (int m = 0; m < 16; ++m){
      float4 xv = *(const float4*)&xs[m*128 + k];
      acc[m] = fmaf(xv.x, w0, acc[m]);
      acc[m] = fmaf(xv.y, w1, acc[m]);
      acc[m] = fmaf(xv.z, w2, acc[m]);
      acc[m] = fmaf(xv.w, w3, acc[m]);
    }
  }
  unsigned outp[8];
  #pragma unroll
  for (int m = 0; m < 8; ++m) outp[m] = pack2(acc[2*m], acc[2*m+1]);
  unsigned short* dst = xwT + (size_t)n*NN + m0;
  ((uint4*)dst)[0] = *(uint4*)&outp[0];
  ((uint4*)dst)[1] = *(uint4*)&outp[4];
}

// ---------------- gemm2: hp[ks] = adj[:, ks-quarter] @ xw[ks-quarter, :] ----------------
// M-tile 128, N full 256, K-split 4 (XCD-locked: ks = blockIdx&3 so each XCD's
// 1MB B-slice stays L2-resident). BK=32, depth-3 DMA pipeline (96KB dyn LDS),
// vmcnt(8) gating -> 2 iterations of latency slack. XOR swizzles -> 2-way banks.
__global__ __launch_bounds__(512, 1) void gemm2_kernel(
    const float* __restrict__ adj, const unsigned short* __restrict__ xwT,
    float* __restrict__ hp)
{
  extern __shared__ char lds[];   // 3 x 32768: A fp32 [128][32] @0, B bf16 [256][32] @16384
  const int t = threadIdx.x;
  const int wave = t >> 6, lane = t & 63, r = lane & 15, q = lane >> 4;
  const int mt = (int)blockIdx.x >> 2, ks = (int)blockIdx.x & 3;
  const int m0 = mt * 128;
  const int kb = ks * 2048;
  const int wm = wave & 1, wn = wave >> 1;

  // A DMA: 2 issues/set, slot s = row*8+g holds src K-group g^(row&7)
  const int arow = t >> 3, ag = t & 7;
  const float* asrcA = adj + (size_t)(m0 + arow)*NN + kb + ((ag ^ (arow & 7)) << 2);
  const float* asrcB = asrcA + (size_t)64*NN;
  // B DMA: 2 issues/set, slot s = nl*4+g holds src K-group g^((nl>>1)&3)
  const int bnl = t >> 2, bg = t & 3;
  const unsigned short* bsrcA = xwT + (size_t)bnl*NN + kb + ((bg ^ ((bnl >> 1) & 3)) << 3);
  const unsigned short* bsrcB = bsrcA + (size_t)128*NN;
  const int dA0 = t*16, dA1 = 8192 + t*16, dB0 = 16384 + t*16, dB1 = 24576 + t*16;

  f32x4 acc[4][4];
  #pragma unroll
  for (int mi = 0; mi < 4; ++mi)
    #pragma unroll
    for (int ni = 0; ni < 4; ++ni) acc[mi][ni] = zero4();

  // prologue: sets 0,1,2 (12 loads/wave outstanding)
  #pragma unroll
  for (int s = 0; s < 3; ++s){
    char* L = lds + s*32768;
    ASYNC16(asrcA + s*32, L + dA0);
    ASYNC16(asrcB + s*32, L + dA1);
    ASYNC16(bsrcA + s*32, L + dB0);
    ASYNC16(bsrcB + s*32, L + dB1);
  }

  // fragment offsets
  int aoff[4][2], boff[4];
  #pragma unroll
  for (int mi = 0; mi < 4; ++mi){
    int row = wm*64 + mi*16 + r;
    aoff[mi][0] = row*32 + (((2*q)   ^ (row & 7)) << 2);
    aoff[mi][1] = row*32 + (((2*q+1) ^ (row & 7)) << 2);
  }
  #pragma unroll
  for (int ni = 0; ni < 4; ++ni){
    int nl = wn*64 + ni*16 + r;
    boff[ni] = nl*4 + (q ^ ((nl >> 1) & 3));
  }

  int rb = 0;
  for (int k = 0; k < 64; ++k){
    if (k < 62) { WAITVM8; } else if (k == 62) { WAITVM4; } else { WAITVM0; }
    BARRIER;
    char* Lb = lds + rb*32768;
    const float* Af = (const float*)Lb;
    const uint4* Bf = (const uint4*)(Lb + 16384);
    float4 pa[4][2];
    FragU fb[4];
    #pragma unroll
    for (int mi = 0; mi < 4; ++mi){
      pa[mi][0] = *(const float4*)(Af + aoff[mi][0]);
      pa[mi][1] = *(const float4*)(Af + aoff[mi][1]);
    }
    #pragma unroll
    for (int ni = 0; ni < 4; ++ni) fb[ni].u4 = Bf[boff[ni]];
    WAITLGKM0;
    BARRIER;
    if (k < 61){
      int ko = (k + 3) * 32;
      ASYNC16(asrcA + ko, Lb + dA0);
      ASYNC16(asrcB + ko, Lb + dA1);
      ASYNC16(bsrcA + ko, Lb + dB0);
      ASYNC16(bsrcB + ko, Lb + dB1);
    }
    FragU fa[4];
    #pragma unroll
    for (int mi = 0; mi < 4; ++mi){
      fa[mi].u[0] = pack2rn(pa[mi][0].x, pa[mi][0].y);
      fa[mi].u[1] = pack2rn(pa[mi][0].z, pa[mi][0].w);
      fa[mi].u[2] = pack2rn(pa[mi][1].x, pa[mi][1].y);
      fa[mi].u[3] = pack2rn(pa[mi][1].z, pa[mi][1].w);
    }
    #pragma unroll
    for (int mi = 0; mi < 4; ++mi)
      #pragma unroll
      for (int ni = 0; ni < 4; ++ni)
        acc[mi][ni] = __builtin_amdgcn_mfma_f32_16x16x32_bf16(fa[mi].v, fb[ni].v, acc[mi][ni], 0, 0, 0);
    rb = (rb == 2) ? 0 : rb + 1;
  }

  float* hpo = hp + (size_t)ks * ((size_t)NN * DM);
  #pragma unroll
  for (int mi = 0; mi < 4; ++mi)
    #pragma unroll
    for (int ni = 0; ni < 4; ++ni){
      const int n = wn*64 + ni*16 + r;
      #pragma unroll
      for (int jr = 0; jr < 4; ++jr){
        const int m = m0 + wm*64 + mi*16 + q*4 + jr;
        hpo[(size_t)m*DM + n] = acc[mi][ni][jr];
      }
    }
}

// ---------------- hred: h = relu(sum of 4 partials + bias) -> bf16, + BN stats ----------------
__global__ __launch_bounds__(256) void hred_kernel(
    const float* __restrict__ hp, const float* __restrict__ b_gcn,
    unsigned short* __restrict__ hb, float* __restrict__ bns, float* __restrict__ bns2)
{
  const size_t NND = (size_t)NN * DM;
  const int c = threadIdx.x;
  const int m0 = blockIdx.x * 32;
  const float bias = b_gcn[c];
  float s1 = 0.f, s2 = 0.f;
  #pragma unroll 8
  for (int rr = 0; rr < 32; ++rr){
    size_t idx = (size_t)(m0 + rr)*DM + c;
    float v = hp[idx] + hp[NND + idx] + hp[2*NND + idx] + hp[3*NND + idx] + bias;
    v = fmaxf(v, 0.f);
    hb[idx] = f2bf(v);
    s1 += v; s2 += v*v;
  }
  atomicAdd(bns + c, s1);
  atomicAdd(bns2 + c, s2);
}

// ---------------- bnapply: hbnb = BN(hb) bf16 ----------------
__global__ __launch_bounds__(256) void bnapply_kernel(
    const unsigned short* __restrict__ hb, const float* __restrict__ s1, const float* __restrict__ s2,
    const float* __restrict__ gamma, const float* __restrict__ beta,
    unsigned short* __restrict__ hbnb)
{
  int base = (blockIdx.x*256 + threadIdx.x) * 2;
  int c0 = base & (DM - 1);
  ushort2 hv = *(const ushort2*)(hb + base);
  float mA = s1[c0] * (1.f/NN),   mB = s1[c0+1] * (1.f/NN);
  float vA = s2[c0] * (1.f/NN) - mA*mA, vB = s2[c0+1] * (1.f/NN) - mB*mB;
  float iA = rsqrtf(vA + 1e-5f), iB = rsqrtf(vB + 1e-5f);
  float a = (bf2f(hv.x) - mA)*iA*gamma[c0]   + beta[c0];
  float b = (bf2f(hv.y) - mB)*iB*gamma[c0+1] + beta[c0+1];
  ushort2 o; o.x = f2bf(a); o.y = f2bf(b);
  *(ushort2*)(hbnb + base) = o;
}

// ---------------- gemm3: [xm|z] = hbnb @ w_in^T (M=8192,K=256,N=1024), bf16 out ----------------
__global__ __launch_bounds__(256) void gemm3_kernel(
    const unsigned short* __restrict__ Ab, const unsigned short* __restrict__ Wb,
    unsigned short* __restrict__ xmb, unsigned short* __restrict__ zb)
{
  __shared__ uint4 alds[2048];  // 64 rows x 32 slots (swizzled), 32 KB
  const int t = threadIdx.x;
  const int wave = t >> 6, lane = t & 63, r = lane & 15, q = lane >> 4;
  const int mb = ((int)blockIdx.x & 127) * 64;
  const int nb = ((int)blockIdx.x >> 7) * 128;
  const int wm = wave & 1, wn = wave >> 1;

  #pragma unroll
  for (int j = 0; j < 8; ++j){
    int si = j*256 + t;
    int row = si >> 5, dg = si & 31;
    int sg = dg ^ (row & 31);
    ASYNC16(Ab + (size_t)(mb + row)*DM + sg*8, (char*)alds + si*16);
  }
  __syncthreads();

  f32x4 acc[2][4];
  #pragma unroll
  for (int mi = 0; mi < 2; ++mi)
    #pragma unroll
    for (int ni = 0; ni < 4; ++ni) acc[mi][ni] = zero4();

  const unsigned short* bp[4];
  #pragma unroll
  for (int ni = 0; ni < 4; ++ni)
    bp[ni] = Wb + (size_t)(nb + wn*64 + ni*16 + r)*DM + q*8;
  FragU fb[4];
  #pragma unroll
  for (int ni = 0; ni < 4; ++ni) fb[ni].u4 = *(const uint4*)bp[ni];

  #pragma unroll
  for (int it = 0; it < 8; ++it){
    FragU fbn[4];
    if (it < 7){
      #pragma unroll
      for (int ni = 0; ni < 4; ++ni) fbn[ni].u4 = *(const uint4*)(bp[ni] + (it+1)*32);
    }
    FragU fa[2];
    #pragma unroll
    for (int mi = 0; mi < 2; ++mi){
      int row = wm*32 + mi*16 + r;
      int g = it*4 + q;
      fa[mi].u4 = alds[row*32 + (g ^ (row & 31))];
    }
    #pragma unroll
    for (int mi = 0; mi < 2; ++mi)
      #pragma unroll
      for (int ni = 0; ni < 4; ++ni)
        acc[mi][ni] = __builtin_amdgcn_mfma_f32_16x16x32_bf16(fa[mi].v, fb[ni].v, acc[mi][ni], 0, 0, 0);
    if (it < 7){
      #pragma unroll
      for (int ni = 0; ni < 4; ++ni) fb[ni] = fbn[ni];
    }
  }
  #pragma unroll
  for (int mi = 0; mi < 2; ++mi)
    #pragma unroll
    for (int ni = 0; ni < 4; ++ni){
      int nc = nb + wn*64 + ni*16 + r;
      unsigned short* dst = (nc < 512) ? (xmb + nc) : (zb + (nc - 512));
      #pragma unroll
      for (int jr = 0; jr < 4; ++jr){
        int m = mb + wm*32 + mi*16 + q*4 + jr;
        dst[(size_t)m*DI] = f2bf(acc[mi][ni][jr]);
      }
    }
}

// ---------------- conv: depthwise causal D=4 + SiLU, register row-window ----------------
__global__ __launch_bounds__(256) void conv_kernel(
    const unsigned short* __restrict__ xmb, const float* __restrict__ conv_w, const float* __restrict__ conv_b,
    float* __restrict__ xc, unsigned short* __restrict__ xcb)
{
  const int d0 = threadIdx.x * 2;
  const int n0 = blockIdx.x * 32;
  float4 wa = *(const float4*)(conv_w + (size_t)d0*4);
  float4 wb = *(const float4*)(conv_w + (size_t)d0*4 + 4);
  float2 bias = *(const float2*)(conv_b + d0);
  float x0a=0.f,x1a=0.f,x2a=0.f, x0b=0.f,x1b=0.f,x2b=0.f;
  #pragma unroll
  for (int j = 0; j < 3; ++j){
    int n = n0 - 3 + j;
    float va = 0.f, vb = 0.f;
    if (n >= 0){
      ushort2 u = *(const ushort2*)(xmb + (size_t)n*DI + d0);
      va = bf2f(u.x); vb = bf2f(u.y);
    }
    if (j == 0){ x0a = va; x0b = vb; }
    else if (j == 1){ x1a = va; x1b = vb; }
    else { x2a = va; x2b = vb; }
  }
  for (int j = 0; j < 32; ++j){
    int n = n0 + j;
    ushort2 u = *(const ushort2*)(xmb + (size_t)n*DI + d0);
    float x3a = bf2f(u.x), x3b = bf2f(u.y);
    float sa = bias.x + wa.x*x0a + wa.y*x1a + wa.z*x2a + wa.w*x3a;
    float sb = bias.y + wb.x*x0b + wb.y*x1b + wb.z*x2b + wb.w*x3b;
    float va = sa * sigmoidf_(sa);
    float vb = sb * sigmoidf_(sb);
    *(float2*)(xc + (size_t)n*DI + d0) = make_float2(va, vb);
    ushort2 o; o.x = f2bf(va); o.y = f2bf(vb);
    *(ushort2*)(xcb + (size_t)n*DI + d0) = o;
    x0a=x1a; x1a=x2a; x2a=x3a;
    x0b=x1b; x1b=x2b; x2b=x3b;
  }
}

// ---------------- gemm4: x_dbl = xc @ w_xproj^T (M=8192,K=512,N=48) ----------------
__global__ __launch_bounds__(256) void gemm4_kernel(
    const unsigned short* __restrict__ Ab, const unsigned short* __restrict__ Wb, float* __restrict__ xdbl)
{
  __shared__ uint4 alds[2048];  // 32 rows x 64 slots, 32 KB
  const int t = threadIdx.x;
  const int wave = t >> 6, lane = t & 63, r = lane & 15, q = lane >> 4;
  const int m0 = (int)blockIdx.x * 32;
  #pragma unroll
  for (int j = 0; j < 8; ++j){
    int si = j*256 + t;
    int row = si >> 6, dg = si & 63;
    int sg = dg ^ (row & 31);
    ASYNC16(Ab + (size_t)(m0 + row)*DI + sg*8, (char*)alds + si*16);
  }
  __syncthreads();
  f32x4 acc[2][3];
  #pragma unroll
  for (int mi = 0; mi < 2; ++mi)
    #pragma unroll
    for (int ni = 0; ni < 3; ++ni) acc[mi][ni] = zero4();
  const int kq = wave * 128;
  const unsigned short* bp[3];
  #pragma unroll
  for (int ni = 0; ni < 3; ++ni) bp[ni] = Wb + (size_t)(ni*16 + r)*DI + kq + q*8;
  FragU fb[3];
  #pragma unroll
  for (int ni = 0; ni < 3; ++ni) fb[ni].u4 = *(const uint4*)bp[ni];
  #pragma unroll
  for (int it = 0; it < 4; ++it){
    FragU fbn[3];
    if (it < 3){
      #pragma unroll
      for (int ni = 0; ni < 3; ++ni) fbn[ni].u4 = *(const uint4*)(bp[ni] + (it+1)*32);
    }
    FragU fa[2];
    #pragma unroll
    for (int mi = 0; mi < 2; ++mi){
      int row = mi*16 + r;
      int g = (kq >> 3) + it*4 + q;
      fa[mi].u4 = alds[row*64 + (g ^ (row & 31))];
    }
    #pragma unroll
    for (int mi = 0; mi < 2; ++mi)
      #pragma unroll
      for (int ni = 0; ni < 3; ++ni)
        acc[mi][ni] = __builtin_amdgcn_mfma_f32_16x16x32_bf16(fa[mi].v, fb[ni].v, acc[mi][ni], 0, 0, 0);
    if (it < 3){
      #pragma unroll
      for (int ni = 0; ni < 3; ++ni) fb[ni] = fbn[ni];
    }
  }
  __syncthreads();
  float* red = (float*)alds;
  if (wave > 0){
    int base = ((wave - 1)*64 + lane)*24;
    #pragma unroll
    for (int mi = 0; mi < 2; ++mi)
      #pragma unroll
      for (int ni = 0; ni < 3; ++ni)
        #pragma unroll
        for (int jr = 0; jr < 4; ++jr)
          red[base + (mi*3 + ni)*4 + jr] = acc[mi][ni][jr];
  }
  __syncthreads();
  if (wave == 0){
    #pragma unroll
    for (int w = 0; w < 3; ++w){
      int base = (w*64 + lane)*24;
      #pragma unroll
      for (int mi = 0; mi < 2; ++mi)
        #pragma unroll
        for (int ni = 0; ni < 3; ++ni)
          #pragma unroll
          for (int jr = 0; jr < 4; ++jr)
            acc[mi][ni][jr] += red[base + (mi*3 + ni)*4 + jr];
    }
    #pragma unroll
    for (int mi = 0; mi < 2; ++mi)
      #pragma unroll
      for (int ni = 0; ni < 3; ++ni)
        #pragma unroll
        for (int jr = 0; jr < 4; ++jr)
          xdbl[(size_t)(m0 + mi*16 + q*4 + jr)*48 + ni*16 + r] = acc[mi][ni][jr];
  }
}

// ---------------- dt = softplus(dt_r @ w_dt^T + b_dt), 64-row strips ----------------
__global__ __launch_bounds__(256) void dt_kernel(
    const float* __restrict__ xdbl, const float* __restrict__ w_dt, const float* __restrict__ b_dt,
    float* __restrict__ dt)
{
  __shared__ float xr[64*16];
  const int t = threadIdx.x;
  const int dg = (int)blockIdx.x & 1;
  const int n0 = ((int)blockIdx.x >> 1) * 64;
  const int d = dg*256 + t;
  #pragma unroll
  for (int j = 0; j < 4; ++j){
    int idx = t + 256*j;
    xr[idx] = xdbl[(size_t)(n0 + (idx >> 4))*48 + (idx & 15)];
  }
  __syncthreads();
  const float4* wp = (const float4*)(w_dt + (size_t)d*16);
  float4 w0 = wp[0], w1 = wp[1], w2 = wp[2], w3 = wp[3];
  float bias = b_dt[d];
  for (int j = 0; j < 64; ++j){
    const float4* xp = (const float4*)(xr + j*16);
    float4 a0 = xp[0], a1 = xp[1], a2 = xp[2], a3 = xp[3];
    float a = bias;
    a += w0.x*a0.x + w0.y*a0.y + w0.z*a0.z + w0.w*a0.w;
    a += w1.x*a1.x + w1.y*a1.y + w1.z*a1.z + w1.w*a1.w;
    a += w2.x*a2.x + w2.y*a2.y + w2.z*a2.z + w2.w*a2.w;
    a += w3.x*a3.x + w3.y*a3.y + w3.z*a3.z + w3.w*a3.w;
    float o = (a > 20.f) ? a : log1pf(__expf(a));
    dt[(size_t)(n0 + j)*DI + d] = o;
  }
}

// ---------------- scanA: per-chunk local recurrence -> interleaved {P,F} ----------------
__global__ __launch_bounds__(256) void scanA_kernel(
    const float* __restrict__ dt, const float* __restrict__ xc,
    const float* __restrict__ xdbl, const float* __restrict__ A_log,
    float2* __restrict__ PF)
{
  __shared__ float Bs[CL*DST];
  const int t = threadIdx.x;
  const int c = (int)blockIdx.x >> 1;
  const int d = (((int)blockIdx.x & 1) << 8) + t;
  #pragma unroll
  for (int j = 0; j < 2; ++j){
    int idx = t + 256*j;
    Bs[idx] = xdbl[(size_t)(c*CL + (idx >> 4))*48 + 16 + (idx & 15)];
  }
  __syncthreads();
  float Av[DST], hs[DST];
  {
    const float4* Ap = (const float4*)(A_log + (size_t)d*DST);
    #pragma unroll
    for (int s4 = 0; s4 < 4; ++s4){
      float4 a4 = Ap[s4];
      Av[s4*4+0] = -__expf(a4.x); Av[s4*4+1] = -__expf(a4.y);
      Av[s4*4+2] = -__expf(a4.z); Av[s4*4+3] = -__expf(a4.w);
    }
  }
  #pragma unroll
  for (int s = 0; s < DST; ++s) hs[s] = 0.f;
  float sdt = 0.f;
  const size_t rb = (size_t)c*CL*DI + d;
  float dtv = dt[rb], xcv = xc[rb];
  for (int tt = 0; tt < CL; ++tt){
    float dtn = 0.f, xcn = 0.f;
    if (tt + 1 < CL){
      dtn = dt[rb + (size_t)(tt+1)*DI];
      xcn = xc[rb + (size_t)(tt+1)*DI];
    }
    float u = dtv * xcv;
    sdt += dtv;
    float bv[DST];
    *(float4*)&bv[0]  = *(const float4*)&Bs[tt*16];
    *(float4*)&bv[4]  = *(const float4*)&Bs[tt*16 + 4];
    *(float4*)&bv[8]  = *(const float4*)&Bs[tt*16 + 8];
    *(float4*)&bv[12] = *(const float4*)&Bs[tt*16 + 12];
    #pragma unroll
    for (int s = 0; s < DST; ++s)
      hs[s] = __expf(dtv * Av[s]) * hs[s] + u * bv[s];
    dtv = dtn; xcv = xcn;
  }
  float4* out = (float4*)(PF + (size_t)c*(DI*DST) + (size_t)d*DST);
  #pragma unroll
  for (int j = 0; j < 8; ++j){
    float4 v;
    v.x = __expf(Av[2*j] * sdt);   v.y = hs[2*j];
    v.z = __expf(Av[2*j+1] * sdt); v.w = hs[2*j+1];
    out[j] = v;
  }
}

// ---------------- scanB: sequential carry across 256 chunks, batched prefetch ----------------
__global__ __launch_bounds__(128) void scanB_kernel(
    const float2* __restrict__ PF, float* __restrict__ Cy)
{
  const int ds = (int)blockIdx.x*128 + (int)threadIdx.x;
  float2 A0[16], A1[16];
  #pragma unroll
  for (int j = 0; j < 16; ++j) A0[j] = PF[(size_t)j*8192 + ds];
  #pragma unroll
  for (int j = 0; j < 16; ++j) A1[j] = PF[(size_t)(16 + j)*8192 + ds];
  float cy = 0.f;
  Cy[ds] = 0.f;
  #pragma unroll
  for (int g = 0; g < 16; ++g){
    #pragma unroll
    for (int j = 0; j < 16; ++j){
      int i = g*16 + j;
      if (i < NC - 1){
        float2 pf = (g & 1) ? A1[j] : A0[j];
        cy = pf.x * cy + pf.y;
        Cy[(size_t)(i + 1)*8192 + ds] = cy;
      }
    }
    int gn = g + 2;
    if (gn < 16){
      #pragma unroll
      for (int j = 0; j < 16; ++j){
        float2 v = PF[(size_t)(gn*16 + j)*8192 + ds];
        if (g & 1) A1[j] = v; else A0[j] = v;
      }
    }
  }
}

// ---------------- scanC: recompute with carry, emit gated y (bf16) ----------------
__global__ __launch_bounds__(256) void scanC_kernel(
    const float* __restrict__ dt, const float* __restrict__ xc,
    const float* __restrict__ xdbl, const float* __restrict__ A_log,
    const float* __restrict__ Cy, const float* __restrict__ Dskip,
    const unsigned short* __restrict__ zb, unsigned short* __restrict__ yb)
{
  __shared__ float Bs[CL*DST];
  __shared__ float Cs[CL*DST];
  const int t = threadIdx.x;
  const int c = (int)blockIdx.x >> 1;
  const int d = (((int)blockIdx.x & 1) << 8) + t;
  #pragma unroll
  for (int j = 0; j < 2; ++j){
    int idx = t + 256*j;
    int tg = c*CL + (idx >> 4);
    Bs[idx] = xdbl[(size_t)tg*48 + 16 + (idx & 15)];
    Cs[idx] = xdbl[(size_t)tg*48 + 32 + (idx & 15)];
  }
  __syncthreads();
  float Av[DST], hs[DST];
  {
    const float4* Ap = (const float4*)(A_log + (size_t)d*DST);
    #pragma unroll
    for (int s4 = 0; s4 < 4; ++s4){
      float4 a4 = Ap[s4];
      Av[s4*4+0] = -__expf(a4.x); Av[s4*4+1] = -__expf(a4.y);
      Av[s4*4+2] = -__expf(a4.z); Av[s4*4+3] = -__expf(a4.w);
    }
  }
  {
    const float4* hp4 = (const float4*)(Cy + (size_t)c*(DI*DST) + (size_t)d*DST);
    #pragma unroll
    for (int s4 = 0; s4 < 4; ++s4){
      float4 h4 = hp4[s4];
      hs[s4*4+0] = h4.x; hs[s4*4+1] = h4.y; hs[s4*4+2] = h4.z; hs[s4*4+3] = h4.w;
    }
  }
  const float Dv = Dskip[d];
  const size_t rb = (size_t)c*CL*DI + d;
  float dtv = dt[rb], xcv = xc[rb];
  unsigned short zv0 = zb[rb];
  for (int tt = 0; tt < CL; ++tt){
    float dtn = 0.f, xcn = 0.f;
    unsigned short zn = 0;
    if (tt + 1 < CL){
      dtn = dt[rb + (size_t)(tt+1)*DI];
      xcn = xc[rb + (size_t)(tt+1)*DI];
      zn  = zb[rb + (size_t)(tt+1)*DI];
    }
    float u = dtv * xcv;
    float bv[DST], cv[DST];
    *(float4*)&bv[0]  = *(const float4*)&Bs[tt*16];
    *(float4*)&bv[4]  = *(const float4*)&Bs[tt*16 + 4];
    *(float4*)&bv[8]  = *(const float4*)&Bs[tt*16 + 8];
    *(float4*)&bv[12] = *(const float4*)&Bs[tt*16 + 12];
    *(float4*)&cv[0]  = *(const float4*)&Cs[tt*16];
    *(float4*)&cv[4]  = *(const float4*)&Cs[tt*16 + 4];
    *(float4*)&cv[8]  = *(const float4*)&Cs[tt*16 + 8];
    *(float4*)&cv[12] = *(const float4*)&Cs[tt*16 + 12];
    float y0 = 0.f, y1 = 0.f;
    #pragma unroll
    for (int s = 0; s < DST; s += 2){
      hs[s]   = __expf(dtv * Av[s])   * hs[s]   + u * bv[s];
      hs[s+1] = __expf(dtv * Av[s+1]) * hs[s+1] + u * bv[s+1];
      y0 += hs[s]   * cv[s];
      y1 += hs[s+1] * cv[s+1];
    }
    float z = bf2f(zv0);
    float yf = ((y0 + y1) + Dv * xcv) * (z * sigmoidf_(z));
    yb[rb + (size_t)tt*DI] = f2bf(yf);
    dtv = dtn; xcv = xcn; zv0 = zn;
  }
}

// ---------------- gemm5: out = y @ w_out^T + hbn (M=8192,K=512,N=256) ----------------
__global__ __launch_bounds__(512) void gemm5_kernel(
    const unsigned short* __restrict__ yb, const unsigned short* __restrict__ Wb,
    const unsigned short* __restrict__ hbnb, float* __restrict__ out)
{
  __shared__ uint4 alds[2048];  // 32 rows x 64 slots, 32 KB
  const int t = threadIdx.x;
  const int wave = t >> 6, lane = t & 63, r = lane & 15, q = lane >> 4;
  const int m0 = (int)blockIdx.x * 32;
  #pragma unroll
  for (int j = 0; j < 4; ++j){
    int si = j*512 + t;
    int row = si >> 6, dg = si & 63;
    int sg = dg ^ (row & 31);
    ASYNC16(yb + (size_t)(m0 + row)*DI + sg*8, (char*)alds + si*16);
  }
  __syncthreads();
  f32x4 acc[2][2];
  #pragma unroll
  for (int mi = 0; mi < 2; ++mi)
    #pragma unroll
    for (int ni = 0; ni < 2; ++ni) acc[mi][ni] = zero4();
  const int nw = wave * 32;
  const unsigned short* bp0 = Wb + (size_t)(nw + r)*DI + q*8;
  const unsigned short* bp1 = Wb + (size_t)(nw + 16 + r)*DI + q*8;
  FragU fb0, fb1;
  fb0.u4 = *(const uint4*)bp0;
  fb1.u4 = *(const uint4*)bp1;
  #pragma unroll
  for (int it = 0; it < 16; ++it){
    FragU fn0, fn1;
    if (it < 15){
      fn0.u4 = *(const uint4*)(bp0 + (it+1)*32);
      fn1.u4 = *(const uint4*)(bp1 + (it+1)*32);
    }
    FragU fa[2];
    #pragma unroll
    for (int mi = 0; mi < 2; ++mi){
      int row = mi*16 + r;
      int g = it*4 + q;
      fa[mi].u4 = alds[row*64 + (g ^ (row & 31))];
    }
    acc[0][0] = __builtin_amdgcn_mfma_f32_16x16x32_bf16(fa[0].v, fb0.v, acc[0][0], 0, 0, 0);
    acc[0][1] = __builtin_amdgcn_mfma_f32_16x16x32_bf16(fa[0].v, fb1.v, acc[0][1], 0, 0, 0);
    acc[1][0] = __builtin_amdgcn_mfma_f32_16x16x32_bf16(fa[1].v, fb0.v, acc[1][0], 0, 0, 0);
    acc[1][1] = __builtin_amdgcn_mfma_f32_16x16x32_bf16(fa[1].v, fb1.v, acc[1][1], 0, 0, 0);
    if (it < 15){ fb0 = fn0; fb1 = fn1; }
  }
  #pragma unroll
  for (int mi = 0; mi < 2; ++mi)
    #pragma unroll
    for (int ni = 0; ni < 2; ++ni){
      const int n = nw + ni*16 + r;
      #pragma unroll
      for (int jr = 0; jr < 4; ++jr){
        const int m = m0 + mi*16 + q*4 + jr;
        size_t idx = (size_t)m*DM + n;
        out[idx] = acc[mi][ni][jr] + bf2f(hbnb[idx]);
      }
    }
}

// ---------------- launch ----------------
extern "C" void kernel_launch(void* const* d_in, const int* in_sizes, int n_in,
                              void* d_out, int out_size, void* d_ws, size_t ws_size,
                              hipStream_t stream)
{
  const float* x      = (const float*)d_in[0];
  const float* adj    = (const float*)d_in[1];
  const float* w_gcn  = (const float*)d_in[2];
  const float* b_gcn  = (const float*)d_in[3];
  const float* gamma  = (const float*)d_in[4];
  const float* beta   = (const float*)d_in[5];
  const float* w_in   = (const float*)d_in[6];
  const float* conv_w = (const float*)d_in[7];
  const float* conv_b = (const float*)d_in[8];
  const float* w_xp   = (const float*)d_in[9];
  const float* w_dt   = (const float*)d_in[10];
  const float* b_dt   = (const float*)d_in[11];
  const float* A_log  = (const float*)d_in[12];
  const float* D_skip = (const float*)d_in[13];
  const float* w_out  = (const float*)d_in[14];
  float* out = (float*)d_out;
  char* ws = (char*)d_ws;
  if (ws_size < WS_NEED) return;

  unsigned short* xwT   = (unsigned short*)(ws + OFF_XWT);
  float*          hp    = (float*)(ws + OFF_HP);
  unsigned short* hb    = (unsigned short*)(ws + OFF_HB);
  unsigned short* hbnb  = (unsigned short*)(ws + OFF_HBNB);
  unsigned short* winb  = (unsigned short*)(ws + OFF_WINB);
  unsigned short* wxpb  = (unsigned short*)(ws + OFF_WXPB);
  unsigned short* woutb = (unsigned short*)(ws + OFF_WOUTB);
  unsigned short* xmb   = (unsigned short*)(ws + OFF_XMB);
  unsigned short* zb    = (unsigned short*)(ws + OFF_ZB);
  float*          xc    = (float*)(ws + OFF_XC);
  unsigned short* xcb   = (unsigned short*)(ws + OFF_XCB);
  float*          xdbl  = (float*)(ws + OFF_XDBL);
  float*          dtb   = (float*)(ws + OFF_DT);
  float2*         PF    = (float2*)(ws + OFF_PF);
  float*          Cy    = (float*)(ws + OFF_CY);
  unsigned short* yb    = (unsigned short*)(ws + OFF_YB);
  float*          bns   = (float*)(ws + OFF_BNS);
  float*          bns2  = (float*)(ws + OFF_BNS2);

  hipMemsetAsync(bns, 0, 2*256*sizeof(float), stream);

  // allow 96KB dynamic LDS for gemm2 (idempotent, graph-capture safe: not a stream op)
  hipFuncSetAttribute((const void*)gemm2_kernel,
                      hipFuncAttributeMaxDynamicSharedMemorySize, 98304);

  prep_kernel   <<<1024, 256, 0, stream>>>(w_in, w_xp, w_out, winb, wxpb, woutb);
  gemm1_kernel  <<<512,  256, 0, stream>>>(x, w_gcn, xwT);
  gemm2_kernel  <<<256,  512, 98304, stream>>>(adj, xwT, hp);
  hred_kernel   <<<256,  256, 0, stream>>>(hp, b_gcn, hb, bns, bns2);
  bnapply_kernel<<<4096, 256, 0, stream>>>(hb, bns, bns2, gamma, beta, hbnb);
  gemm3_kernel  <<<1024, 256, 0, stream>>>(hbnb, winb, xmb, zb);
  conv_kernel   <<<256,  256, 0, stream>>>(xmb, conv_w, conv_b, xc, xcb);
  gemm4_kernel  <<<256,  256, 0, stream>>>(xcb, wxpb, xdbl);
  dt_kernel     <<<256,  256, 0, stream>>>(xdbl, w_dt, b_dt, dtb);
  scanA_kernel  <<<512,  256, 0, stream>>>(dtb, xc, xdbl, A_log, PF);
  scanB_kernel  <<<64,   128, 0, stream>>>(PF, Cy);
  scanC_kernel  <<<512,  256, 0, stream>>>(dtb, xc, xdbl, A_log, Cy, D_skip, zb, yb);
  gemm5_kernel  <<<256,  512, 0, stream>>>(yb, woutb, hbnb, out);
}